// Round 14
// baseline (991.260 us; speedup 1.0000x reference)
//
#include <hip/hip_runtime.h>

static constexpr int N_ = 8192;
static constexpr int B_ = 2;
static constexpr int K_ = 16;

typedef __attribute__((ext_vector_type(8))) short bf16x8;
typedef __attribute__((ext_vector_type(4))) float f32x4;

__device__ __forceinline__ short f2bf(float f) {
  unsigned int u = __float_as_uint(f);
  unsigned int r = (u + 0x7FFFu + ((u >> 16) & 1u)) >> 16;
  return (short)r;
}
__device__ __forceinline__ float bf2f(short h) {
  return __uint_as_float(((unsigned int)(unsigned short)h) << 16);
}

// ---------------------------------------------------------------------------
// KNN: merged full scan (R12 config — best measured 137us). 1 query/wave,
// 512-thr block, 2048-pt tile, crossbar __shfl, refresh drain, fma dist,
// scalar self-exclusion.
// ---------------------------------------------------------------------------
__global__ __launch_bounds__(512) void knn_kernel(const float* __restrict__ coords,
                                                  int* __restrict__ oidx,
                                                  float* __restrict__ odist) {
  __shared__ float4 pts[2048];
  const int b = blockIdx.y;
  const int wv = threadIdx.x >> 6;
  const int lane = threadIdx.x & 63;
  const int q = blockIdx.x * 8 + wv;
  const float* cb = coords + (size_t)b * N_ * 3;
  const float qx = cb[q * 3 + 0], qy = cb[q * 3 + 1], qz = cb[q * 3 + 2];
  const float qsq = fmaf(qx, qx, fmaf(qy, qy, qz * qz));
  const int qblk = q & ~63;
  const unsigned long long qbit = ~(1ull << (q & 63));
  float kd = INFINITY;
  int ki = 0;
  float tau = INFINITY;
  for (int t0 = 0; t0 < N_; t0 += 2048) {
    __syncthreads();
    for (int i = threadIdx.x; i < 2048; i += 512) {
      const int p = t0 + i;
      const float x = cb[p * 3 + 0], y = cb[p * 3 + 1], z = cb[p * 3 + 2];
      pts[i] = make_float4(x, y, z, fmaf(x, x, fmaf(y, y, z * z)));
    }
    __syncthreads();
    for (int s = 0; s < 2048; s += 64) {
      const float4 p = pts[s + lane];
      const int base = t0 + s;
      const float dot = fmaf(qx, p.x, fmaf(qy, p.y, qz * p.z));
      const float d2 = fmaf(-2.0f, dot, qsq + p.w);
      unsigned long long m = __ballot(d2 < tau);
      if (base == qblk) m &= qbit;
      while (m) {
        const int src = __builtin_ctzll(m);  // ascending index -> tie stability
        const float dc = __shfl(d2, src);
        const int jc = base + src;
        const float sd = __shfl_up(kd, 1);
        const int si = __shfl_up(ki, 1);
        const bool c1 = kd > dc;
        const bool c2 = (lane > 0) && (sd > dc);
        kd = c1 ? (c2 ? sd : dc) : kd;
        ki = c1 ? (c2 ? si : jc) : ki;
        m &= (m - 1);
        tau = __shfl(kd, 15);
        m &= __ballot(d2 < tau);
      }
    }
  }
  if (lane < 16) {
    oidx[((size_t)b * N_ + q) * K_ + lane] = ki;
    odist[((size_t)b * N_ + q) * K_ + lane] = fmaxf(kd, 0.0f);
  }
}

// ---------------------------------------------------------------------------
// Moments helpers
// ---------------------------------------------------------------------------
__device__ __forceinline__ float snn_get(const float* SNN, int a, int b) {
  const int i = a < b ? a : b, j = a < b ? b : a;
  return SNN[i == 0 ? j : (i == 1 ? 2 + j : 3 + j)];
}
__device__ __forceinline__ float mom_mean(int i, const float* C, const float* SN, float Sd) {
  if (i < 3) return 16.0f * C[i];
  if (i < 6) return SN[i - 3];
  if (i < 9) return 16.0f * C[i - 6] - SN[i - 6];
  return Sd;
}
__device__ __forceinline__ float mom_prod(int i, int j, const float* C, const float* SN,
                                          const float* SNN, float Sd, float Sdd, const float* SND) {
  const int ti = i < 3 ? 0 : (i < 6 ? 1 : (i < 9 ? 2 : 3));
  const int tj = j < 3 ? 0 : (j < 6 ? 1 : (j < 9 ? 2 : 3));
  const int a = (ti == 3) ? 0 : (i - ti * 3);
  const int bb = (tj == 3) ? 0 : (j - tj * 3);
  if (ti == 0 && tj == 0) return 16.0f * C[a] * C[bb];
  if (ti == 0 && tj == 1) return C[a] * SN[bb];
  if (ti == 0 && tj == 2) return C[a] * (16.0f * C[bb] - SN[bb]);
  if (ti == 0 && tj == 3) return C[a] * Sd;
  if (ti == 1 && tj == 1) return snn_get(SNN, a, bb);
  if (ti == 1 && tj == 2) return C[bb] * SN[a] - snn_get(SNN, a, bb);
  if (ti == 1 && tj == 3) return SND[a];
  if (ti == 2 && tj == 2) return 16.0f * C[a] * C[bb] - C[a] * SN[bb] - C[bb] * SN[a] + snn_get(SNN, a, bb);
  if (ti == 2 && tj == 3) return C[a] * Sd - SND[a];
  return Sdd;
}

// ---------------------------------------------------------------------------
// PREP: blocks 0-10 weight conversion; blocks 11..266 k-parallel moments
// ---------------------------------------------------------------------------
template <int CI, int CO>
__device__ __forceinline__ void conv_frag_seg(const float* __restrict__ w, short* __restrict__ H,
                                              short* __restrict__ L, int tid, int nthr) {
  constexpr int NT = CO / 16;
  for (int i = tid; i < CI * CO; i += nthr) {
    const int j = i & 7, l = (i >> 3) & 63, tmp = i >> 9;
    const int tt = tmp % NT, cc = tmp / NT;
    const int c = cc * 32 + (l >> 4) * 8 + j;
    const int o = tt * 16 + (l & 15);
    const float v = w[o * CI + c];
    const short h = f2bf(v);
    H[i] = h;
    L[i] = f2bf(v - bf2f(h));
  }
}

__global__ __launch_bounds__(256) void prep_kernel(
    const float* __restrict__ pw1, const float* __restrict__ pw2,
    short* __restrict__ wB1, short* __restrict__ wB2,
    const float* __restrict__ wm1, short* __restrict__ f1H, short* __restrict__ f1L,
    const float* __restrict__ wrs, short* __restrict__ fRH, short* __restrict__ fRL,
    const float* __restrict__ coords, const int* __restrict__ knn_i,
    const float* __restrict__ knn_d, double* __restrict__ mom) {
  const int blk = blockIdx.x;
  if (blk < 9) {
    if (blk < 4) {
      for (int i = blk * 256 + threadIdx.x; i < 128 * 128; i += 1024) wB1[i] = f2bf(pw1[i]);
    } else if (blk == 4) {
      for (int i = threadIdx.x; i < 64 * 64; i += 256) wB2[i] = f2bf(pw2[i]);
    } else if (blk == 5) {
      conv_frag_seg<32, 64>(wm1, f1H, f1L, threadIdx.x, 256);
    } else if (blk == 6) {
      conv_frag_seg<32, 128>(wrs, fRH, fRL, threadIdx.x, 256);
    } else {
      conv_frag_seg<32, 128>(wrs, fRH, fRL, (blk - 7) * 256 + threadIdx.x, 512);  // redundant overlap ok
    }
    return;
  }
  __shared__ float sh[16][65];
  const int mb = blk - 9;
  const int k = threadIdx.x & 15;
  const int pl = threadIdx.x >> 4;
  float accv = 0.0f;
  for (int batch = 0; batch < 4; ++batch) {
    const int pt = (mb * 4 + batch) * 16 + pl;
    const int b = pt >> 13, n = pt & (N_ - 1);
    const float* cb = coords + (size_t)b * N_ * 3;
    const float cx = cb[n * 3 + 0], cy = cb[n * 3 + 1], cz = cb[n * 3 + 2];
    const int id = knn_i[(size_t)pt * K_ + k];
    const float dd = knn_d[(size_t)pt * K_ + k];
    const float nx = cb[id * 3 + 0], ny = cb[id * 3 + 1], nz = cb[id * 3 + 2];
    float v[14] = {nx, ny, nz, nx * nx, nx * ny, nx * nz, ny * ny, ny * nz, nz * nz,
                   dd, dd * dd, nx * dd, ny * dd, nz * dd};
#pragma unroll
    for (int e = 0; e < 14; ++e) {
      v[e] += __shfl_xor(v[e], 1);
      v[e] += __shfl_xor(v[e], 2);
      v[e] += __shfl_xor(v[e], 4);
      v[e] += __shfl_xor(v[e], 8);
    }
    if (k == 0) {
      const float C[3] = {cx, cy, cz};
      const float SN[3] = {v[0], v[1], v[2]};
      const float SNN[6] = {v[3], v[4], v[5], v[6], v[7], v[8]};
      const float Sd = v[9], Sdd = v[10];
      const float SND[3] = {v[11], v[12], v[13]};
      float m65[65];
      int e = 0;
#pragma unroll
      for (int i = 0; i < 10; ++i) m65[e++] = mom_mean(i, C, SN, Sd);
#pragma unroll
      for (int i = 0; i < 10; ++i)
#pragma unroll
        for (int j = i; j < 10; ++j) m65[e++] = mom_prod(i, j, C, SN, SNN, Sd, Sdd, SND);
#pragma unroll
      for (int q2 = 0; q2 < 65; ++q2) sh[pl][q2] = m65[q2];
    }
    __syncthreads();
    if (threadIdx.x < 65) {
      float s = 0.0f;
#pragma unroll
      for (int r = 0; r < 16; ++r) s += sh[r][threadIdx.x];
      accv += s;
    }
    __syncthreads();
  }
  if (threadIdx.x < 65) atomicAdd(&mom[threadIdx.x], (double)accv);
}

// ---------------------------------------------------------------------------
// MFMA GEMM body with last-block BN-affine finalize (hi/lo bf16 split)
// ---------------------------------------------------------------------------
template <int CI, int CO>
__device__ __forceinline__ void gemm_body(const float* __restrict__ in,
                                          const short* __restrict__ fragH,
                                          const short* __restrict__ fragL,
                                          const float* __restrict__ bias,
                                          float* __restrict__ out,
                                          double* __restrict__ sacc,
                                          unsigned* __restrict__ cnt, int nblk,
                                          const float* __restrict__ gam, const float* __restrict__ bet,
                                          float* __restrict__ af, float* __restrict__ bf,
                                          int blk, void* smem) {
  constexpr int NT = CO / 16;
  constexpr int NC = CI / 32;
  float (*part)[CO][2] = (float (*)[CO][2])smem;
  const int wv = threadIdx.x >> 6, l = threadIdx.x & 63;
  const int col = l & 15, quad = l >> 4;
  const int p0 = blk * 64 + wv * 16;
  const int pt = p0 + col;
  f32x4 d[NT];
#pragma unroll
  for (int t = 0; t < NT; ++t) {
    const float bv = bias[t * 16 + col];
    d[t][0] = bv; d[t][1] = bv; d[t][2] = bv; d[t][3] = bv;
  }
#pragma unroll
  for (int cc = 0; cc < NC; ++cc) {
    const int b = pt >> 13, n = pt & (N_ - 1);
    const float* ip = in + ((size_t)b * CI + cc * 32 + quad * 8) * N_ + n;
    float xv[8];
#pragma unroll
    for (int j = 0; j < 8; ++j) xv[j] = ip[(size_t)j * N_];
    union { bf16x8 v; short u[8]; } AH, AL;
#pragma unroll
    for (int j = 0; j < 8; ++j) {
      const short h = f2bf(xv[j]);
      AH.u[j] = h;
      AL.u[j] = f2bf(xv[j] - bf2f(h));
    }
#pragma unroll
    for (int t = 0; t < NT; ++t) {
      const size_t fo = ((size_t)(cc * NT + t) * 64 + l) * 8;
      const bf16x8 BH = *(const bf16x8*)(fragH + fo);
      const bf16x8 BL = *(const bf16x8*)(fragL + fo);
      d[t] = __builtin_amdgcn_mfma_f32_16x16x32_bf16(AH.v, BH, d[t], 0, 0, 0);
      d[t] = __builtin_amdgcn_mfma_f32_16x16x32_bf16(AH.v, BL, d[t], 0, 0, 0);
      d[t] = __builtin_amdgcn_mfma_f32_16x16x32_bf16(AL.v, BH, d[t], 0, 0, 0);
    }
  }
#pragma unroll
  for (int t = 0; t < NT; ++t) {
#pragma unroll
    for (int r = 0; r < 4; ++r)
      out[(size_t)(p0 + quad * 4 + r) * CO + t * 16 + col] = d[t][r];
    float s1 = d[t][0] + d[t][1] + d[t][2] + d[t][3];
    float s2 = d[t][0] * d[t][0] + d[t][1] * d[t][1] + d[t][2] * d[t][2] + d[t][3] * d[t][3];
    s1 += __shfl_xor(s1, 16); s1 += __shfl_xor(s1, 32);
    s2 += __shfl_xor(s2, 16); s2 += __shfl_xor(s2, 32);
    if (quad == 0) { part[wv][t * 16 + col][0] = s1; part[wv][t * 16 + col][1] = s2; }
  }
  __syncthreads();
  if (threadIdx.x < CO) {
    const int o = threadIdx.x;
    atomicAdd(&sacc[o], (double)(part[0][o][0] + part[1][o][0] + part[2][o][0] + part[3][o][0]));
    atomicAdd(&sacc[CO + o], (double)(part[0][o][1] + part[1][o][1] + part[2][o][1] + part[3][o][1]));
  }
  // last-block finalize: sacc totals -> float affine (af, bf)
  __threadfence();
  __syncthreads();
  __shared__ unsigned lastv;
  if (threadIdx.x == 0) lastv = atomicAdd(cnt, 1u);
  __syncthreads();
  if (lastv == (unsigned)(nblk - 1) && threadIdx.x < CO) {
    const int o = threadIdx.x;
    const double s1 = atomicAdd(&sacc[o], 0.0);
    const double s2 = atomicAdd(&sacc[CO + o], 0.0);
    const double cd = (double)(B_ * N_);
    const double mean = s1 / cd;
    const double var = s2 / cd - mean * mean;
    const double av = (double)gam[o] / sqrt(var + 1e-5);
    af[o] = (float)av;
    bf[o] = (float)((double)bet[o] - av * mean);
  }
}

// ---------------------------------------------------------------------------
// GEMMA: blocks 0-255 mlp1, 256-511 res, block 512 lse setup (w8 fold)
// ---------------------------------------------------------------------------
__global__ __launch_bounds__(256) void gemmA_kernel(
    const float* __restrict__ features,
    const short* __restrict__ f1H, const short* __restrict__ f1L,
    const float* __restrict__ mlp1_b, float* __restrict__ y1, double* __restrict__ sacc1,
    const float* __restrict__ mlp1_g, const float* __restrict__ mlp1_t,
    float* __restrict__ af1, float* __restrict__ bf1, unsigned* __restrict__ cnt1,
    const short* __restrict__ fRH, const short* __restrict__ fRL,
    const float* __restrict__ res_b, float* __restrict__ yr, double* __restrict__ saccR,
    const float* __restrict__ res_g, const float* __restrict__ res_t,
    float* __restrict__ afR, float* __restrict__ bfR, unsigned* __restrict__ cntR,
    const double* __restrict__ mom,
    const float* __restrict__ w1, const float* __restrict__ b1,
    const float* __restrict__ g1, const float* __restrict__ t1,
    const float* __restrict__ w2, const float* __restrict__ b2,
    const float* __restrict__ g2, const float* __restrict__ t2,
    float* __restrict__ w1f8, float* __restrict__ w2f8) {
  __shared__ float part[4][128][2];
  if (blockIdx.x < 256) {
    gemm_body<32, 64>(features, f1H, f1L, mlp1_b, y1, sacc1, cnt1, 256,
                      mlp1_g, mlp1_t, af1, bf1, blockIdx.x, (void*)part);
    return;
  }
  if (blockIdx.x < 512) {
    gemm_body<32, 128>(features, fRH, fRL, res_b, yr, saccR, cntR, 256,
                       res_g, res_t, afR, bfR, blockIdx.x - 256, (void*)part);
    return;
  }
  const int t = threadIdx.x;
  double* mu = (double*)part;
  double* S = mu + 10;
  const double cnt = (double)B_ * N_ * K_;
  if (t < 10) mu[t] = mom[t] / cnt;
  if (t < 55) {
    int e = t, i = 0;
    while (e >= 10 - i) { e -= 10 - i; ++i; }
    const int j = i + e;
    const double v = mom[10 + t] / cnt;
    S[i * 10 + j] = v;
    S[j * 10 + i] = v;
  }
  __syncthreads();
  const float *w, *bias, *gg, *bt;
  float *wf;
  int c;
  if (t < 64) { w = w1; bias = b1; gg = g1; bt = t1; wf = w1f8; c = t; }
  else if (t < 96) { w = w2; bias = b2; gg = g2; bt = t2; wf = w2f8; c = t - 64; }
  else return;
  double wd[10];
#pragma unroll
  for (int d = 0; d < 10; ++d) wd[d] = (double)w[c * 10 + d];
  const double cbv = (double)bias[c];
  double mz = cbv;
  for (int d = 0; d < 10; ++d) mz += wd[d] * mu[d];
  double e2 = cbv * cbv;
  for (int d = 0; d < 10; ++d) e2 += 2.0 * cbv * wd[d] * mu[d];
  for (int d = 0; d < 10; ++d)
    for (int e = 0; e < 10; ++e) e2 += wd[d] * wd[e] * S[d * 10 + e];
  const double var = e2 - mz * mz;
  const double a = (double)gg[c] / sqrt(var + 1e-5);
  const double shift = (double)bt[c] - a * mz;
  wf[c * 8 + 0] = (float)(a * (wd[0] + wd[6]));
  wf[c * 8 + 1] = (float)(a * (wd[1] + wd[7]));
  wf[c * 8 + 2] = (float)(a * (wd[2] + wd[8]));
  wf[c * 8 + 3] = (float)(a * (wd[3] - wd[6]));
  wf[c * 8 + 4] = (float)(a * (wd[4] - wd[7]));
  wf[c * 8 + 5] = (float)(a * (wd[5] - wd[8]));
  wf[c * 8 + 6] = (float)(a * wd[9]);
  wf[c * 8 + 7] = (float)(a * cbv + shift);
}

// ---------------------------------------------------------------------------
// POOL1 + fused mlpp1: pooled stays in LDS; Phase E 128->32 gemm in exact
// fp32 -> y2 + 64-group partials; last block reduces partials -> af2/bf2.
// ---------------------------------------------------------------------------
__global__ __launch_bounds__(256) void pool1_kernel(
    const float* __restrict__ coords, const int* __restrict__ knn_i, const float* __restrict__ knn_d,
    const float* __restrict__ w8,
    const float* __restrict__ feat, const float* __restrict__ af1, const float* __restrict__ bf1,
    const short* __restrict__ wB, const float* __restrict__ pb,
    const float* __restrict__ w2, const float* __restrict__ b2,
    const float* __restrict__ g2c, const float* __restrict__ t2c,
    float* __restrict__ y2, double* __restrict__ y2part,
    unsigned* __restrict__ cnt, float* __restrict__ af2, float* __restrict__ bf2) {
  constexpr int CSF = 64, CF = 64, C = 128, CP = 132, NT = 8, NC = 4;
  __shared__ float xcat[4][16][CP];
  __shared__ float4 sp4[4][16];
  __shared__ float4 spc[4];
  __shared__ float plds[4][C];
  __shared__ float sh2[4][32][2];
  const int g = threadIdx.x >> 6;
  const int l = threadIdx.x & 63;
  const int quad = l >> 4, col = l & 15;
  const int pid = blockIdx.x * 4 + g;
  const int b = pid >> 13, n = pid & (N_ - 1);
  const float* cb = coords + (size_t)b * N_ * 3;

  if (l < 16) {
    const int id = knn_i[(size_t)pid * K_ + l];
    const float dd = knn_d[(size_t)pid * K_ + l];
    sp4[g][l] = make_float4(cb[id * 3 + 0], cb[id * 3 + 1], cb[id * 3 + 2], dd);
    if (l == 0) spc[g] = make_float4(cb[n * 3 + 0], cb[n * 3 + 1], cb[n * 3 + 2], 0.0f);
  }
  {  // feat (y1): precomputed affine + LeakyReLU(0.2)
    float v = feat[(size_t)pid * CF + l];
    v = af1[l] * v + bf1[l];
    v = (v >= 0.0f) ? v : 0.2f * v;
#pragma unroll
    for (int j = 0; j < 16; ++j) xcat[g][j][CSF + l] = v;
  }
  __syncthreads();
  {  // sf channels: z = (P.c + b') + Q.n + wd*d, relu
    const float4 wA = *(const float4*)(w8 + l * 8);
    const float4 wBv = *(const float4*)(w8 + l * 8 + 4);
    const float4 C4 = spc[g];
    const float tterm = wBv.w + wA.x * C4.x + wA.y * C4.y + wA.z * C4.z;
#pragma unroll
    for (int k = 0; k < 16; ++k) {
      const float4 nk = sp4[g][k];
      const float z = tterm + wA.w * nk.x + wBv.x * nk.y + wBv.y * nk.z + wBv.z * nk.w;
      xcat[g][k][l] = fmaxf(z, 0.0f);
    }
  }
  __syncthreads();
  f32x4 d[NT];
#pragma unroll
  for (int t = 0; t < NT; ++t) {
    const float pbv = pb[t * 16 + col];
    d[t][0] = pbv; d[t][1] = pbv; d[t][2] = pbv; d[t][3] = pbv;
  }
#pragma unroll
  for (int cc = 0; cc < NC; ++cc) {
    const float* xr = &xcat[g][col][cc * 32 + quad * 8];
    const float4 xa = *(const float4*)xr;
    const float4 xb = *(const float4*)(xr + 4);
    union { bf16x8 v; short u[8]; } A;
    A.u[0] = f2bf(xa.x); A.u[1] = f2bf(xa.y); A.u[2] = f2bf(xa.z); A.u[3] = f2bf(xa.w);
    A.u[4] = f2bf(xb.x); A.u[5] = f2bf(xb.y); A.u[6] = f2bf(xb.z); A.u[7] = f2bf(xb.w);
#pragma unroll
    for (int t = 0; t < NT; ++t) {
      const bf16x8 Bv = *(const bf16x8*)(wB + (size_t)(t * 16 + col) * C + cc * 32 + quad * 8);
      d[t] = __builtin_amdgcn_mfma_f32_16x16x32_bf16(A.v, Bv, d[t], 0, 0, 0);
    }
  }
#pragma unroll
  for (int t = 0; t < NT; ++t) {
    float mx = fmaxf(fmaxf(d[t][0], d[t][1]), fmaxf(d[t][2], d[t][3]));
    mx = fmaxf(mx, __shfl_xor(mx, 16));
    mx = fmaxf(mx, __shfl_xor(mx, 32));
    float e0 = __expf(d[t][0] - mx), e1 = __expf(d[t][1] - mx);
    float e2 = __expf(d[t][2] - mx), e3 = __expf(d[t][3] - mx);
    float s = e0 + e1 + e2 + e3;
    s += __shfl_xor(s, 16);
    s += __shfl_xor(s, 32);
    const int o = t * 16 + col;
    float part = e0 * xcat[g][quad * 4 + 0][o] + e1 * xcat[g][quad * 4 + 1][o] +
                 e2 * xcat[g][quad * 4 + 2][o] + e3 * xcat[g][quad * 4 + 3][o];
    part += __shfl_xor(part, 16);
    part += __shfl_xor(part, 32);
    if (quad == 0) plds[g][o] = part / s;
  }
  __syncthreads();
  // Phase E: y2 = mlpp1(pooled) exact fp32
  if (l < 32) {
    float acc = b2[l];
    const float* wr = w2 + l * 128;
#pragma unroll 8
    for (int c4 = 0; c4 < 32; ++c4) {
      const float4 w4 = *(const float4*)(wr + c4 * 4);
      const float4 p4 = *(const float4*)&plds[g][c4 * 4];
      acc += w4.x * p4.x + w4.y * p4.y + w4.z * p4.z + w4.w * p4.w;
    }
    y2[(size_t)pid * 32 + l] = acc;
    sh2[g][l][0] = acc;
    sh2[g][l][1] = acc * acc;
  }
  __syncthreads();
  if (threadIdx.x < 32) {
    const int o = threadIdx.x;
    const double s1 = (double)sh2[0][o][0] + sh2[1][o][0] + sh2[2][o][0] + sh2[3][o][0];
    const double s2 = (double)sh2[0][o][1] + sh2[1][o][1] + sh2[2][o][1] + sh2[3][o][1];
    const int gid = blockIdx.x & 63;
    atomicAdd(&y2part[(size_t)(gid * 32 + o) * 2 + 0], s1);
    atomicAdd(&y2part[(size_t)(gid * 32 + o) * 2 + 1], s2);
  }
  __threadfence();
  __syncthreads();
  __shared__ unsigned lastv;
  if (threadIdx.x == 0) lastv = atomicAdd(cnt, 1u);
  __syncthreads();
  if (lastv == (unsigned)(gridDim.x - 1) && threadIdx.x < 32) {
    const int o = threadIdx.x;
    double s1 = 0.0, s2 = 0.0;
    for (int gg = 0; gg < 64; ++gg) {
      s1 += atomicAdd(&y2part[(size_t)(gg * 32 + o) * 2 + 0], 0.0);
      s2 += atomicAdd(&y2part[(size_t)(gg * 32 + o) * 2 + 1], 0.0);
    }
    const double cd = (double)(B_ * N_);
    const double mean = s1 / cd;
    const double var = s2 / cd - mean * mean;
    const double av = (double)g2c[o] / sqrt(var + 1e-5);
    af2[o] = (float)av;
    bf2[o] = (float)((double)t2c[o] - av * mean);
  }
}

// ---------------------------------------------------------------------------
// POOL2 + fused mlp2: reads precomputed af2/bf2; Phase E 64->128 exact fp32
// -> y3 + 64-group partials; last block -> af3/bf3.
// ---------------------------------------------------------------------------
__global__ __launch_bounds__(256) void pool2_kernel(
    const float* __restrict__ coords, const int* __restrict__ knn_i, const float* __restrict__ knn_d,
    const float* __restrict__ w8,
    const float* __restrict__ feat, const float* __restrict__ af2, const float* __restrict__ bf2,
    const short* __restrict__ wB, const float* __restrict__ pb,
    const float* __restrict__ w3, const float* __restrict__ b3,
    const float* __restrict__ g3c, const float* __restrict__ t3c,
    float* __restrict__ y3, double* __restrict__ y3part,
    unsigned* __restrict__ cnt, float* __restrict__ af3, float* __restrict__ bf3) {
  constexpr int CSF = 32, CF = 32, C = 64, CP = 68, NT = 4, NC = 2;
  __shared__ float xcat[4][16][CP];
  __shared__ float4 sp4[4][16];
  __shared__ float4 spc[4];
  __shared__ float p2lds[4][C];
  __shared__ float sh3[4][128][2];
  const int g = threadIdx.x >> 6;
  const int l = threadIdx.x & 63;
  const int quad = l >> 4, col = l & 15;
  const int pid = blockIdx.x * 4 + g;
  const int b = pid >> 13, n = pid & (N_ - 1);
  const float* cb = coords + (size_t)b * N_ * 3;

  if (l < 16) {
    const int id = knn_i[(size_t)pid * K_ + l];
    const float dd = knn_d[(size_t)pid * K_ + l];
    sp4[g][l] = make_float4(cb[id * 3 + 0], cb[id * 3 + 1], cb[id * 3 + 2], dd);
    if (l == 0) spc[g] = make_float4(cb[n * 3 + 0], cb[n * 3 + 1], cb[n * 3 + 2], 0.0f);
  }
  if (l < CF) {  // feat (y2): precomputed affine + ReLU
    float v = feat[(size_t)pid * CF + l];
    v = af2[l] * v + bf2[l];
    v = fmaxf(v, 0.0f);
#pragma unroll
    for (int j = 0; j < 16; ++j) xcat[g][j][CSF + l] = v;
  }
  if (l >= 32) {  // sf channels on lanes 32..63 (c = l-32)
    const int c = l - 32;
    const float4 wA = *(const float4*)(w8 + c * 8);
    const float4 wBv = *(const float4*)(w8 + c * 8 + 4);
    const float4 C4 = spc[g];
    // note: spc written by lane 0 this phase — need sync before use
  }
  __syncthreads();
  if (l < CSF) {
    const float4 wA = *(const float4*)(w8 + l * 8);
    const float4 wBv = *(const float4*)(w8 + l * 8 + 4);
    const float4 C4 = spc[g];
    const float tterm = wBv.w + wA.x * C4.x + wA.y * C4.y + wA.z * C4.z;
#pragma unroll
    for (int k = 0; k < 16; ++k) {
      const float4 nk = sp4[g][k];
      const float z = tterm + wA.w * nk.x + wBv.x * nk.y + wBv.y * nk.z + wBv.z * nk.w;
      xcat[g][k][l] = fmaxf(z, 0.0f);
    }
  }
  __syncthreads();
  f32x4 d[NT];
#pragma unroll
  for (int t = 0; t < NT; ++t) {
    const float pbv = pb[t * 16 + col];
    d[t][0] = pbv; d[t][1] = pbv; d[t][2] = pbv; d[t][3] = pbv;
  }
#pragma unroll
  for (int cc = 0; cc < NC; ++cc) {
    const float* xr = &xcat[g][col][cc * 32 + quad * 8];
    const float4 xa = *(const float4*)xr;
    const float4 xb = *(const float4*)(xr + 4);
    union { bf16x8 v; short u[8]; } A;
    A.u[0] = f2bf(xa.x); A.u[1] = f2bf(xa.y); A.u[2] = f2bf(xa.z); A.u[3] = f2bf(xa.w);
    A.u[4] = f2bf(xb.x); A.u[5] = f2bf(xb.y); A.u[6] = f2bf(xb.z); A.u[7] = f2bf(xb.w);
#pragma unroll
    for (int t = 0; t < NT; ++t) {
      const bf16x8 Bv = *(const bf16x8*)(wB + (size_t)(t * 16 + col) * C + cc * 32 + quad * 8);
      d[t] = __builtin_amdgcn_mfma_f32_16x16x32_bf16(A.v, Bv, d[t], 0, 0, 0);
    }
  }
#pragma unroll
  for (int t = 0; t < NT; ++t) {
    float mx = fmaxf(fmaxf(d[t][0], d[t][1]), fmaxf(d[t][2], d[t][3]));
    mx = fmaxf(mx, __shfl_xor(mx, 16));
    mx = fmaxf(mx, __shfl_xor(mx, 32));
    float e0 = __expf(d[t][0] - mx), e1 = __expf(d[t][1] - mx);
    float e2 = __expf(d[t][2] - mx), e3 = __expf(d[t][3] - mx);
    float s = e0 + e1 + e2 + e3;
    s += __shfl_xor(s, 16);
    s += __shfl_xor(s, 32);
    const int o = t * 16 + col;
    float part = e0 * xcat[g][quad * 4 + 0][o] + e1 * xcat[g][quad * 4 + 1][o] +
                 e2 * xcat[g][quad * 4 + 2][o] + e3 * xcat[g][quad * 4 + 3][o];
    part += __shfl_xor(part, 16);
    part += __shfl_xor(part, 32);
    if (quad == 0) p2lds[g][o] = part / s;
  }
  __syncthreads();
  // Phase E: y3 = mlp2(pooled2) exact fp32; lane l -> channels 2l, 2l+1
  {
    const int o0 = 2 * l, o1 = 2 * l + 1;
    float a0 = b3[o0], a1 = b3[o1];
    const float* w0 = w3 + (size_t)o0 * 64;
    const float* w1 = w3 + (size_t)o1 * 64;
#pragma unroll 4
    for (int c4 = 0; c4 < 16; ++c4) {
      const float4 p4 = *(const float4*)&p2lds[g][c4 * 4];
      const float4 wa = *(const float4*)(w0 + c4 * 4);
      const float4 wb = *(const float4*)(w1 + c4 * 4);
      a0 += wa.x * p4.x + wa.y * p4.y + wa.z * p4.z + wa.w * p4.w;
      a1 += wb.x * p4.x + wb.y * p4.y + wb.z * p4.z + wb.w * p4.w;
    }
    *(float2*)(y3 + (size_t)pid * 128 + o0) = make_float2(a0, a1);
    sh3[g][o0][0] = a0; sh3[g][o0][1] = a0 * a0;
    sh3[g][o1][0] = a1; sh3[g][o1][1] = a1 * a1;
  }
  __syncthreads();
  if (threadIdx.x < 128) {
    const int o = threadIdx.x;
    const double s1 = (double)sh3[0][o][0] + sh3[1][o][0] + sh3[2][o][0] + sh3[3][o][0];
    const double s2 = (double)sh3[0][o][1] + sh3[1][o][1] + sh3[2][o][1] + sh3[3][o][1];
    const int gid = blockIdx.x & 63;
    atomicAdd(&y3part[(size_t)(gid * 128 + o) * 2 + 0], s1);
    atomicAdd(&y3part[(size_t)(gid * 128 + o) * 2 + 1], s2);
  }
  __threadfence();
  __syncthreads();
  __shared__ unsigned lastv;
  if (threadIdx.x == 0) lastv = atomicAdd(cnt, 1u);
  __syncthreads();
  if (lastv == (unsigned)(gridDim.x - 1) && threadIdx.x < 128) {
    const int o = threadIdx.x;
    double s1 = 0.0, s2 = 0.0;
    for (int gg = 0; gg < 64; ++gg) {
      s1 += atomicAdd(&y3part[(size_t)(gg * 128 + o) * 2 + 0], 0.0);
      s2 += atomicAdd(&y3part[(size_t)(gg * 128 + o) * 2 + 1], 0.0);
    }
    const double cd = (double)(B_ * N_);
    const double mean = s1 / cd;
    const double var = s2 / cd - mean * mean;
    const double av = (double)g3c[o] / sqrt(var + 1e-5);
    af3[o] = (float)av;
    bf3[o] = (float)((double)t3c[o] - av * mean);
  }
}

// ---------------------------------------------------------------------------
// Final: relu(affine(y3|yr)) — affines precomputed floats; LDS transpose
// ---------------------------------------------------------------------------
__global__ __launch_bounds__(256) void final_kernel(const float* __restrict__ y3,
                                                    const float* __restrict__ yr,
                                                    const float* __restrict__ af3, const float* __restrict__ bf3,
                                                    const float* __restrict__ afR, const float* __restrict__ bfR,
                                                    float* __restrict__ out) {
  __shared__ float tile[256 * 17];
  const int blk = blockIdx.x;
  const int b = blk >> 9;
  const int n0 = (blk & 511) << 4;
  const int c = threadIdx.x;
  const float* src;
  float av, bv;
  int cc;
  if (c < 128) { src = y3; av = af3[c]; bv = bf3[c]; cc = c; }
  else { src = yr; av = afR[c - 128]; bv = bfR[c - 128]; cc = c - 128; }
#pragma unroll
  for (int nl = 0; nl < 16; ++nl) {
    const float x = av * src[((size_t)(b * N_ + n0 + nl)) * 128 + cc] + bv;
    tile[c * 17 + nl] = fmaxf(x, 0.0f);
  }
  __syncthreads();
  const int np = c & 15, grp = c >> 4;
#pragma unroll
  for (int j = 0; j < 16; ++j) {
    const int c2 = grp * 16 + j;
    out[((size_t)(b * 256 + c2)) * N_ + n0 + np] = tile[c2 * 17 + np];
  }
}

// ---------------------------------------------------------------------------
extern "C" void kernel_launch(void* const* d_in, const int* in_sizes, int n_in,
                              void* d_out, int out_size, void* d_ws, size_t ws_size,
                              hipStream_t stream) {
  (void)in_sizes; (void)n_in; (void)out_size; (void)ws_size;
  const float* coords   = (const float*)d_in[0];
  const float* features = (const float*)d_in[1];
  const float* mlp1_w = (const float*)d_in[2];
  const float* mlp1_b = (const float*)d_in[3];
  const float* mlp1_g = (const float*)d_in[4];
  const float* mlp1_t = (const float*)d_in[5];
  const float* lse1_w = (const float*)d_in[6];
  const float* lse1_b = (const float*)d_in[7];
  const float* lse1_g = (const float*)d_in[8];
  const float* lse1_t = (const float*)d_in[9];
  const float* mlpp1_w = (const float*)d_in[10];
  const float* mlpp1_b = (const float*)d_in[11];
  const float* mlpp1_g = (const float*)d_in[12];
  const float* mlpp1_t = (const float*)d_in[13];
  const float* lse2_w = (const float*)d_in[14];
  const float* lse2_b = (const float*)d_in[15];
  const float* lse2_g = (const float*)d_in[16];
  const float* lse2_t = (const float*)d_in[17];
  const float* mlp2_w = (const float*)d_in[18];
  const float* mlp2_b = (const float*)d_in[19];
  const float* mlp2_g = (const float*)d_in[20];
  const float* mlp2_t = (const float*)d_in[21];
  const float* res_w = (const float*)d_in[22];
  const float* res_b = (const float*)d_in[23];
  const float* res_g = (const float*)d_in[24];
  const float* res_t = (const float*)d_in[25];
  const float* pool1_w = (const float*)d_in[26];
  const float* pool1_b = (const float*)d_in[27];
  const float* pool2_w = (const float*)d_in[28];
  const float* pool2_b = (const float*)d_in[29];

  float* wsf = (float*)d_ws;
  int* knn_i = (int*)d_ws;                 // 262144 ints
  float* knn_d = wsf + 262144;             // 262144
  float* y1 = wsf + 524288;                // (B,N,64)  1048576
  float* y2 = wsf + 1572864;               // (B,N,32)  524288
  float* y3 = wsf + 2097152;               // (B,N,128) 2097152
  float* yr = wsf + 4194304;               // (B,N,128) 2097152
  double* dacc = (double*)(wsf + 6291456);
  double* mom = dacc;                      // 65
  double* sacc_mlp1 = dacc + 65;           // 128
  double* sacc_res = dacc + 193;           // 256
  double* y2part = dacc + 449;             // 4096
  double* y3part = dacc + 4545;            // 16384 -> 20929
  unsigned* cnts = (unsigned*)(dacc + 20929);  // 8 unsigned (zeroed by memset)
  float* fpar = wsf + 6333440;
  float* w1f8 = fpar;                 // 512
  float* w2f8 = w1f8 + 512;           // 256
  float* af1 = w2f8 + 256;            // 64
  float* bf1 = af1 + 64;              // 64
  float* af2 = bf1 + 64;              // 32
  float* bf2 = af2 + 32;              // 32
  float* af3 = bf2 + 32;              // 128
  float* bf3 = af3 + 128;             // 128
  float* afR = bf3 + 128;             // 128
  float* bfR = afR + 128;             // 128
  short* wB1 = (short*)(bfR + 128);   // 16384 shorts
  short* wB2 = wB1 + 16384;           // 4096
  short* f1H = wB2 + 4096;            // 2048
  short* f1L = f1H + 2048;            // 2048
  short* fRH = f1L + 2048;            // 4096
  short* fRL = fRH + 4096;            // 4096

  hipMemsetAsync(dacc, 0, 20936 * sizeof(double), stream);
  knn_kernel<<<dim3(N_ / 8, B_), 512, 0, stream>>>(coords, knn_i, knn_d);
  prep_kernel<<<9 + 256, 256, 0, stream>>>(pool1_w, pool2_w, wB1, wB2,
                                           mlp1_w, f1H, f1L, res_w, fRH, fRL,
                                           coords, knn_i, knn_d, mom);
  gemmA_kernel<<<513, 256, 0, stream>>>(features,
                                        f1H, f1L, mlp1_b, y1, sacc_mlp1,
                                        mlp1_g, mlp1_t, af1, bf1, &cnts[0],
                                        fRH, fRL, res_b, yr, sacc_res,
                                        res_g, res_t, afR, bfR, &cnts[1],
                                        mom,
                                        lse1_w, lse1_b, lse1_g, lse1_t,
                                        lse2_w, lse2_b, lse2_g, lse2_t, w1f8, w2f8);
  pool1_kernel<<<B_ * N_ / 4, 256, 0, stream>>>(coords, knn_i, knn_d, w1f8,
                                                y1, af1, bf1, wB1, pool1_b,
                                                mlpp1_w, mlpp1_b, mlpp1_g, mlpp1_t,
                                                y2, y2part, &cnts[2], af2, bf2);
  pool2_kernel<<<B_ * N_ / 4, 256, 0, stream>>>(coords, knn_i, knn_d, w2f8,
                                                y2, af2, bf2, wB2, pool2_b,
                                                mlp2_w, mlp2_b, mlp2_g, mlp2_t,
                                                y3, y3part, &cnts[3], af3, bf3);
  final_kernel<<<B_ * 512, 256, 0, stream>>>(y3, yr, af3, bf3, afR, bfR, (float*)d_out);
}

// Round 15
// 391.806 us; speedup vs baseline: 2.5300x; 2.5300x over previous
//
#include <hip/hip_runtime.h>

static constexpr int N_ = 8192;
static constexpr int B_ = 2;
static constexpr int K_ = 16;

typedef __attribute__((ext_vector_type(8))) short bf16x8;
typedef __attribute__((ext_vector_type(4))) float f32x4;

__device__ __forceinline__ short f2bf(float f) {
  unsigned int u = __float_as_uint(f);
  unsigned int r = (u + 0x7FFFu + ((u >> 16) & 1u)) >> 16;
  return (short)r;
}
__device__ __forceinline__ float bf2f(short h) {
  return __uint_as_float(((unsigned int)(unsigned short)h) << 16);
}

// ---------------------------------------------------------------------------
// KNN: R3 body verbatim (best full-scan measurement: 127us vs 137 for fmaf
// variant). 1 query/wave, 512-thr block, 2048-pt tile, crossbar __shfl
// (insert chain on LDS pipe), refresh drain, _rn distances, in-lane
// self-exclusion.
// ---------------------------------------------------------------------------
__global__ __launch_bounds__(512) void knn_kernel(const float* __restrict__ coords,
                                                  int* __restrict__ oidx,
                                                  float* __restrict__ odist) {
  __shared__ float4 pts[2048];
  const int b = blockIdx.y;
  const int wv = threadIdx.x >> 6;
  const int lane = threadIdx.x & 63;
  const int q = blockIdx.x * 8 + wv;
  const float* cb = coords + (size_t)b * N_ * 3;
  const float qx = cb[q * 3 + 0], qy = cb[q * 3 + 1], qz = cb[q * 3 + 2];
  const float qsq = __fadd_rn(__fadd_rn(__fmul_rn(qx, qx), __fmul_rn(qy, qy)), __fmul_rn(qz, qz));
  float kd = INFINITY;  // sorted top-16 lives in lanes 0..15 (ascending)
  int ki = 0;
  float tau = INFINITY;
  for (int t0 = 0; t0 < N_; t0 += 2048) {
    __syncthreads();
    for (int i = threadIdx.x; i < 2048; i += 512) {
      const int p = t0 + i;
      const float x = cb[p * 3 + 0], y = cb[p * 3 + 1], z = cb[p * 3 + 2];
      const float sq = __fadd_rn(__fadd_rn(__fmul_rn(x, x), __fmul_rn(y, y)), __fmul_rn(z, z));
      pts[i] = make_float4(x, y, z, sq);
    }
    __syncthreads();
    for (int s = 0; s < 2048; s += 64) {
      const int j = t0 + s + lane;
      const float4 p = pts[s + lane];
      const float dot = __fadd_rn(__fadd_rn(__fmul_rn(qx, p.x), __fmul_rn(qy, p.y)), __fmul_rn(qz, p.z));
      float d2 = __fsub_rn(__fadd_rn(qsq, p.w), __fmul_rn(2.0f, dot));
      if (j == q) d2 = INFINITY;
      unsigned long long m = __ballot(d2 < tau);
      while (m) {
        const int src = __builtin_ctzll(m);  // ascending index -> tie stability
        const float dc = __shfl(d2, src);
        const int jc = t0 + s + src;
        const float sd = __shfl_up(kd, 1);
        const int si = __shfl_up(ki, 1);
        const bool c1 = kd > dc;             // strict: equals keep earlier entries
        const bool c2 = (lane > 0) && (sd > dc);
        kd = c1 ? (c2 ? sd : dc) : kd;
        ki = c1 ? (c2 ? si : jc) : ki;
        m &= (m - 1);
        tau = __shfl(kd, 15);
        m &= __ballot(d2 < tau);
      }
    }
  }
  if (lane < 16) {
    oidx[((size_t)b * N_ + q) * K_ + lane] = ki;
    odist[((size_t)b * N_ + q) * K_ + lane] = fmaxf(kd, 0.0f);
  }
}

// ---------------------------------------------------------------------------
// Moments helpers
// ---------------------------------------------------------------------------
__device__ __forceinline__ float snn_get(const float* SNN, int a, int b) {
  const int i = a < b ? a : b, j = a < b ? b : a;
  return SNN[i == 0 ? j : (i == 1 ? 2 + j : 3 + j)];
}
__device__ __forceinline__ float mom_mean(int i, const float* C, const float* SN, float Sd) {
  if (i < 3) return 16.0f * C[i];
  if (i < 6) return SN[i - 3];
  if (i < 9) return 16.0f * C[i - 6] - SN[i - 6];
  return Sd;
}
__device__ __forceinline__ float mom_prod(int i, int j, const float* C, const float* SN,
                                          const float* SNN, float Sd, float Sdd, const float* SND) {
  const int ti = i < 3 ? 0 : (i < 6 ? 1 : (i < 9 ? 2 : 3));
  const int tj = j < 3 ? 0 : (j < 6 ? 1 : (j < 9 ? 2 : 3));
  const int a = (ti == 3) ? 0 : (i - ti * 3);
  const int bb = (tj == 3) ? 0 : (j - tj * 3);
  if (ti == 0 && tj == 0) return 16.0f * C[a] * C[bb];
  if (ti == 0 && tj == 1) return C[a] * SN[bb];
  if (ti == 0 && tj == 2) return C[a] * (16.0f * C[bb] - SN[bb]);
  if (ti == 0 && tj == 3) return C[a] * Sd;
  if (ti == 1 && tj == 1) return snn_get(SNN, a, bb);
  if (ti == 1 && tj == 2) return C[bb] * SN[a] - snn_get(SNN, a, bb);
  if (ti == 1 && tj == 3) return SND[a];
  if (ti == 2 && tj == 2) return 16.0f * C[a] * C[bb] - C[a] * SN[bb] - C[bb] * SN[a] + snn_get(SNN, a, bb);
  if (ti == 2 && tj == 3) return C[a] * Sd - SND[a];
  return Sdd;
}

// ---------------------------------------------------------------------------
// PREP: blocks 0-10 weight conversion; blocks 11..266 k-parallel moments
// ---------------------------------------------------------------------------
template <int CI, int CO>
__device__ __forceinline__ void conv_frag_seg(const float* __restrict__ w, short* __restrict__ H,
                                              short* __restrict__ L, int tid, int nthr) {
  constexpr int NT = CO / 16;
  for (int i = tid; i < CI * CO; i += nthr) {
    const int j = i & 7, l = (i >> 3) & 63, tmp = i >> 9;
    const int tt = tmp % NT, cc = tmp / NT;
    const int c = cc * 32 + (l >> 4) * 8 + j;
    const int o = tt * 16 + (l & 15);
    const float v = w[o * CI + c];
    const short h = f2bf(v);
    H[i] = h;
    L[i] = f2bf(v - bf2f(h));
  }
}

__global__ __launch_bounds__(256) void prep_kernel(
    const float* __restrict__ pw1, const float* __restrict__ pw2,
    short* __restrict__ wB1, short* __restrict__ wB2,
    const float* __restrict__ wm1, short* __restrict__ f1H, short* __restrict__ f1L,
    const float* __restrict__ wmp, short* __restrict__ f2H, short* __restrict__ f2L,
    const float* __restrict__ wm2, short* __restrict__ f3H, short* __restrict__ f3L,
    const float* __restrict__ wrs, short* __restrict__ fRH, short* __restrict__ fRL,
    const float* __restrict__ coords, const int* __restrict__ knn_i,
    const float* __restrict__ knn_d, double* __restrict__ mom) {
  const int blk = blockIdx.x;
  if (blk < 11) {
    if (blk < 4) {
      for (int i = blk * 256 + threadIdx.x; i < 128 * 128; i += 1024) wB1[i] = f2bf(pw1[i]);
    } else if (blk == 4) {
      for (int i = threadIdx.x; i < 64 * 64; i += 256) wB2[i] = f2bf(pw2[i]);
    } else if (blk == 5) {
      conv_frag_seg<32, 64>(wm1, f1H, f1L, threadIdx.x, 256);
    } else if (blk == 6) {
      conv_frag_seg<128, 32>(wmp, f2H, f2L, threadIdx.x, 256);
    } else if (blk < 9) {
      conv_frag_seg<64, 128>(wm2, f3H, f3L, (blk - 7) * 256 + threadIdx.x, 512);
    } else {
      conv_frag_seg<32, 128>(wrs, fRH, fRL, (blk - 9) * 256 + threadIdx.x, 512);
    }
    return;
  }
  __shared__ float sh[16][65];
  const int mb = blk - 11;
  const int k = threadIdx.x & 15;
  const int pl = threadIdx.x >> 4;
  float accv = 0.0f;
  for (int batch = 0; batch < 4; ++batch) {
    const int pt = (mb * 4 + batch) * 16 + pl;
    const int b = pt >> 13, n = pt & (N_ - 1);
    const float* cb = coords + (size_t)b * N_ * 3;
    const float cx = cb[n * 3 + 0], cy = cb[n * 3 + 1], cz = cb[n * 3 + 2];
    const int id = knn_i[(size_t)pt * K_ + k];
    const float dd = knn_d[(size_t)pt * K_ + k];
    const float nx = cb[id * 3 + 0], ny = cb[id * 3 + 1], nz = cb[id * 3 + 2];
    float v[14] = {nx, ny, nz, nx * nx, nx * ny, nx * nz, ny * ny, ny * nz, nz * nz,
                   dd, dd * dd, nx * dd, ny * dd, nz * dd};
#pragma unroll
    for (int e = 0; e < 14; ++e) {
      v[e] += __shfl_xor(v[e], 1);
      v[e] += __shfl_xor(v[e], 2);
      v[e] += __shfl_xor(v[e], 4);
      v[e] += __shfl_xor(v[e], 8);
    }
    if (k == 0) {
      const float C[3] = {cx, cy, cz};
      const float SN[3] = {v[0], v[1], v[2]};
      const float SNN[6] = {v[3], v[4], v[5], v[6], v[7], v[8]};
      const float Sd = v[9], Sdd = v[10];
      const float SND[3] = {v[11], v[12], v[13]};
      float m65[65];
      int e = 0;
#pragma unroll
      for (int i = 0; i < 10; ++i) m65[e++] = mom_mean(i, C, SN, Sd);
#pragma unroll
      for (int i = 0; i < 10; ++i)
#pragma unroll
        for (int j = i; j < 10; ++j) m65[e++] = mom_prod(i, j, C, SN, SNN, Sd, Sdd, SND);
#pragma unroll
      for (int q2 = 0; q2 < 65; ++q2) sh[pl][q2] = m65[q2];
    }
    __syncthreads();
    if (threadIdx.x < 65) {
      float s = 0.0f;
#pragma unroll
      for (int r = 0; r < 16; ++r) s += sh[r][threadIdx.x];
      accv += s;
    }
    __syncthreads();
  }
  if (threadIdx.x < 65) atomicAdd(&mom[threadIdx.x], (double)accv);
}

// ---------------------------------------------------------------------------
// MFMA GEMM body + standalone kernel (hi/lo bf16 split => ~fp32 accuracy)
// ---------------------------------------------------------------------------
template <int CI, int CO, bool ROWMAJ>
__device__ __forceinline__ void gemm_body(const float* __restrict__ in,
                                          const short* __restrict__ fragH,
                                          const short* __restrict__ fragL,
                                          const float* __restrict__ bias,
                                          float* __restrict__ out,
                                          double* __restrict__ sacc,
                                          int blk, void* smem) {
  constexpr int NT = CO / 16;
  constexpr int NC = CI / 32;
  float (*part)[CO][2] = (float (*)[CO][2])smem;
  const int wv = threadIdx.x >> 6, l = threadIdx.x & 63;
  const int col = l & 15, quad = l >> 4;
  const int p0 = blk * 64 + wv * 16;
  const int pt = p0 + col;
  f32x4 d[NT];
#pragma unroll
  for (int t = 0; t < NT; ++t) {
    const float bv = bias[t * 16 + col];
    d[t][0] = bv; d[t][1] = bv; d[t][2] = bv; d[t][3] = bv;
  }
#pragma unroll
  for (int cc = 0; cc < NC; ++cc) {
    float xv[8];
    if (ROWMAJ) {
      const float* ip = in + (size_t)pt * CI + cc * 32 + quad * 8;
      *(float4*)&xv[0] = *(const float4*)ip;
      *(float4*)&xv[4] = *(const float4*)(ip + 4);
    } else {
      const int b = pt >> 13, n = pt & (N_ - 1);
      const float* ip = in + ((size_t)b * CI + cc * 32 + quad * 8) * N_ + n;
#pragma unroll
      for (int j = 0; j < 8; ++j) xv[j] = ip[(size_t)j * N_];
    }
    union { bf16x8 v; short u[8]; } AH, AL;
#pragma unroll
    for (int j = 0; j < 8; ++j) {
      const short h = f2bf(xv[j]);
      AH.u[j] = h;
      AL.u[j] = f2bf(xv[j] - bf2f(h));
    }
#pragma unroll
    for (int t = 0; t < NT; ++t) {
      const size_t fo = ((size_t)(cc * NT + t) * 64 + l) * 8;
      const bf16x8 BH = *(const bf16x8*)(fragH + fo);
      const bf16x8 BL = *(const bf16x8*)(fragL + fo);
      d[t] = __builtin_amdgcn_mfma_f32_16x16x32_bf16(AH.v, BH, d[t], 0, 0, 0);
      d[t] = __builtin_amdgcn_mfma_f32_16x16x32_bf16(AH.v, BL, d[t], 0, 0, 0);
      d[t] = __builtin_amdgcn_mfma_f32_16x16x32_bf16(AL.v, BH, d[t], 0, 0, 0);
    }
  }
#pragma unroll
  for (int t = 0; t < NT; ++t) {
#pragma unroll
    for (int r = 0; r < 4; ++r)
      out[(size_t)(p0 + quad * 4 + r) * CO + t * 16 + col] = d[t][r];
    float s1 = d[t][0] + d[t][1] + d[t][2] + d[t][3];
    float s2 = d[t][0] * d[t][0] + d[t][1] * d[t][1] + d[t][2] * d[t][2] + d[t][3] * d[t][3];
    s1 += __shfl_xor(s1, 16); s1 += __shfl_xor(s1, 32);
    s2 += __shfl_xor(s2, 16); s2 += __shfl_xor(s2, 32);
    if (quad == 0) { part[wv][t * 16 + col][0] = s1; part[wv][t * 16 + col][1] = s2; }
  }
  __syncthreads();
  if (threadIdx.x < CO) {
    const int o = threadIdx.x;
    atomicAdd(&sacc[o], (double)(part[0][o][0] + part[1][o][0] + part[2][o][0] + part[3][o][0]));
    atomicAdd(&sacc[CO + o], (double)(part[0][o][1] + part[1][o][1] + part[2][o][1] + part[3][o][1]));
  }
}

template <int CI, int CO, bool ROWMAJ>
__global__ __launch_bounds__(256) void gemm_mfma_kernel(const float* __restrict__ in,
                                                        const short* __restrict__ fragH,
                                                        const short* __restrict__ fragL,
                                                        const float* __restrict__ bias,
                                                        float* __restrict__ out,
                                                        double* __restrict__ sacc) {
  __shared__ float part[4][CO][2];
  gemm_body<CI, CO, ROWMAJ>(in, fragH, fragL, bias, out, sacc, blockIdx.x, (void*)part);
}

// ---------------------------------------------------------------------------
// GEMMA: blocks 0-255 mlp1, 256-511 res, block 512 lse setup (w8 fold)
// ---------------------------------------------------------------------------
__global__ __launch_bounds__(256) void gemmA_kernel(
    const float* __restrict__ features,
    const short* __restrict__ f1H, const short* __restrict__ f1L,
    const float* __restrict__ mlp1_b, float* __restrict__ y1, double* __restrict__ sacc1,
    const short* __restrict__ fRH, const short* __restrict__ fRL,
    const float* __restrict__ res_b, float* __restrict__ yr, double* __restrict__ saccR,
    const double* __restrict__ mom,
    const float* __restrict__ w1, const float* __restrict__ b1,
    const float* __restrict__ g1, const float* __restrict__ t1,
    const float* __restrict__ w2, const float* __restrict__ b2,
    const float* __restrict__ g2, const float* __restrict__ t2,
    float* __restrict__ w1f8, float* __restrict__ w2f8) {
  __shared__ float part[4][128][2];
  if (blockIdx.x < 256) {
    gemm_body<32, 64, false>(features, f1H, f1L, mlp1_b, y1, sacc1, blockIdx.x, (void*)part);
    return;
  }
  if (blockIdx.x < 512) {
    gemm_body<32, 128, false>(features, fRH, fRL, res_b, yr, saccR, blockIdx.x - 256, (void*)part);
    return;
  }
  const int t = threadIdx.x;
  double* mu = (double*)part;
  double* S = mu + 10;
  const double cnt = (double)B_ * N_ * K_;
  if (t < 10) mu[t] = mom[t] / cnt;
  if (t < 55) {
    int e = t, i = 0;
    while (e >= 10 - i) { e -= 10 - i; ++i; }
    const int j = i + e;
    const double v = mom[10 + t] / cnt;
    S[i * 10 + j] = v;
    S[j * 10 + i] = v;
  }
  __syncthreads();
  const float *w, *bias, *gg, *bt;
  float *wf;
  int c;
  if (t < 64) { w = w1; bias = b1; gg = g1; bt = t1; wf = w1f8; c = t; }
  else if (t < 96) { w = w2; bias = b2; gg = g2; bt = t2; wf = w2f8; c = t - 64; }
  else return;
  double wd[10];
#pragma unroll
  for (int d = 0; d < 10; ++d) wd[d] = (double)w[c * 10 + d];
  const double cbv = (double)bias[c];
  double mz = cbv;
  for (int d = 0; d < 10; ++d) mz += wd[d] * mu[d];
  double e2 = cbv * cbv;
  for (int d = 0; d < 10; ++d) e2 += 2.0 * cbv * wd[d] * mu[d];
  for (int d = 0; d < 10; ++d)
    for (int e = 0; e < 10; ++e) e2 += wd[d] * wd[e] * S[d * 10 + e];
  const double var = e2 - mz * mz;
  const double a = (double)gg[c] / sqrt(var + 1e-5);
  const double shift = (double)bt[c] - a * mz;
  wf[c * 8 + 0] = (float)(a * (wd[0] + wd[6]));
  wf[c * 8 + 1] = (float)(a * (wd[1] + wd[7]));
  wf[c * 8 + 2] = (float)(a * (wd[2] + wd[8]));
  wf[c * 8 + 3] = (float)(a * (wd[3] - wd[6]));
  wf[c * 8 + 4] = (float)(a * (wd[4] - wd[7]));
  wf[c * 8 + 5] = (float)(a * (wd[5] - wd[8]));
  wf[c * 8 + 6] = (float)(a * wd[9]);
  wf[c * 8 + 7] = (float)(a * cbv + shift);
}

// ---------------------------------------------------------------------------
// Fused LSE + attentive pool, MFMA scores (proven R10/R12 version)
// ---------------------------------------------------------------------------
template <int CSF, int CF>
__global__ __launch_bounds__(256) void pool_kernel(
    const float* __restrict__ coords, const int* __restrict__ knn_i, const float* __restrict__ knn_d,
    const float* __restrict__ w8,
    const float* __restrict__ feat, const double* __restrict__ sfe,
    const float* __restrict__ gfe, const float* __restrict__ tfe,
    const float slope,
    const short* __restrict__ wB, const float* __restrict__ pb,
    float* __restrict__ out) {
  constexpr int C = CSF + CF;
  constexpr int CP = C + 4;
  constexpr int NT = C / 16;
  constexpr int NC = C / 32;
  __shared__ float xcat[4][16][CP];
  __shared__ float4 sp4[4][16];
  __shared__ float4 spc[4];
  const int g = threadIdx.x >> 6;
  const int l = threadIdx.x & 63;
  const int quad = l >> 4, col = l & 15;
  const int pid = blockIdx.x * 4 + g;
  const int b = pid >> 13, n = pid & (N_ - 1);
  const float* cb = coords + (size_t)b * N_ * 3;

  if (l < 16) {
    const int id = knn_i[(size_t)pid * K_ + l];
    const float dd = knn_d[(size_t)pid * K_ + l];
    sp4[g][l] = make_float4(cb[id * 3 + 0], cb[id * 3 + 1], cb[id * 3 + 2], dd);
    if (l == 0) spc[g] = make_float4(cb[n * 3 + 0], cb[n * 3 + 1], cb[n * 3 + 2], 0.0f);
  }
  if (l < CF) {
    const double cnt = (double)(B_ * N_);
    const double mean = sfe[l] / cnt;
    const double var = sfe[CF + l] / cnt - mean * mean;
    const double av = (double)gfe[l] / sqrt(var + 1e-5);
    const float af = (float)av;
    const float bfv = (float)((double)tfe[l] - av * mean);
    float v = feat[(size_t)pid * CF + l];
    v = af * v + bfv;
    v = (v >= 0.0f) ? v : slope * v;
#pragma unroll
    for (int j = 0; j < 16; ++j) xcat[g][j][CSF + l] = v;
  }
  __syncthreads();
  if (l < CSF) {
    const float4 wA = *(const float4*)(w8 + l * 8);      // P0,P1,P2,Q0
    const float4 wBv = *(const float4*)(w8 + l * 8 + 4); // Q1,Q2,wd,b'
    const float4 C4 = spc[g];
    const float tterm = wBv.w + wA.x * C4.x + wA.y * C4.y + wA.z * C4.z;
#pragma unroll
    for (int k = 0; k < 16; ++k) {
      const float4 nk = sp4[g][k];
      const float z = tterm + wA.w * nk.x + wBv.x * nk.y + wBv.y * nk.z + wBv.z * nk.w;
      xcat[g][k][l] = fmaxf(z, 0.0f);
    }
  }
  __syncthreads();
  f32x4 d[NT];
#pragma unroll
  for (int t = 0; t < NT; ++t) {
    const float pbv = pb[t * 16 + col];
    d[t][0] = pbv; d[t][1] = pbv; d[t][2] = pbv; d[t][3] = pbv;
  }
#pragma unroll
  for (int cc = 0; cc < NC; ++cc) {
    const float* xr = &xcat[g][col][cc * 32 + quad * 8];
    const float4 xa = *(const float4*)xr;
    const float4 xb = *(const float4*)(xr + 4);
    union { bf16x8 v; short u[8]; } A;
    A.u[0] = f2bf(xa.x); A.u[1] = f2bf(xa.y); A.u[2] = f2bf(xa.z); A.u[3] = f2bf(xa.w);
    A.u[4] = f2bf(xb.x); A.u[5] = f2bf(xb.y); A.u[6] = f2bf(xb.z); A.u[7] = f2bf(xb.w);
#pragma unroll
    for (int t = 0; t < NT; ++t) {
      const bf16x8 Bv = *(const bf16x8*)(wB + (size_t)(t * 16 + col) * C + cc * 32 + quad * 8);
      d[t] = __builtin_amdgcn_mfma_f32_16x16x32_bf16(A.v, Bv, d[t], 0, 0, 0);
    }
  }
#pragma unroll
  for (int t = 0; t < NT; ++t) {
    float mx = fmaxf(fmaxf(d[t][0], d[t][1]), fmaxf(d[t][2], d[t][3]));
    mx = fmaxf(mx, __shfl_xor(mx, 16));
    mx = fmaxf(mx, __shfl_xor(mx, 32));
    float e0 = __expf(d[t][0] - mx), e1 = __expf(d[t][1] - mx);
    float e2 = __expf(d[t][2] - mx), e3 = __expf(d[t][3] - mx);
    float s = e0 + e1 + e2 + e3;
    s += __shfl_xor(s, 16);
    s += __shfl_xor(s, 32);
    const int o = t * 16 + col;
    float part = e0 * xcat[g][quad * 4 + 0][o] + e1 * xcat[g][quad * 4 + 1][o] +
                 e2 * xcat[g][quad * 4 + 2][o] + e3 * xcat[g][quad * 4 + 3][o];
    part += __shfl_xor(part, 16);
    part += __shfl_xor(part, 32);
    if (quad == 0) out[(size_t)pid * C + o] = part / s;
  }
}

// ---------------------------------------------------------------------------
// Final: relu(affine(y3|yr)) with LDS transpose for coalesced writes
// ---------------------------------------------------------------------------
__global__ __launch_bounds__(256) void final_kernel(const float* __restrict__ y3,
                                                    const float* __restrict__ yr,
                                                    const double* __restrict__ s3,
                                                    const float* __restrict__ g3, const float* __restrict__ t3,
                                                    const double* __restrict__ sr,
                                                    const float* __restrict__ gr, const float* __restrict__ tr,
                                                    float* __restrict__ out) {
  __shared__ float tile[256 * 17];
  const int blk = blockIdx.x;
  const int b = blk >> 9;
  const int n0 = (blk & 511) << 4;
  const int c = threadIdx.x;
  const float* src;
  const double* sa;
  const float *gp, *tp;
  int cc;
  if (c < 128) { src = y3; sa = s3; gp = g3; tp = t3; cc = c; }
  else { src = yr; sa = sr; gp = gr; tp = tr; cc = c - 128; }
  const double cnt = (double)(B_ * N_);
  const double mean = sa[cc] / cnt;
  const double var = sa[128 + cc] / cnt - mean * mean;
  const double avd = (double)gp[cc] / sqrt(var + 1e-5);
  const float av = (float)avd;
  const float bv = (float)((double)tp[cc] - avd * mean);
#pragma unroll
  for (int nl = 0; nl < 16; ++nl) {
    const float x = av * src[((size_t)(b * N_ + n0 + nl)) * 128 + cc] + bv;
    tile[c * 17 + nl] = fmaxf(x, 0.0f);
  }
  __syncthreads();
  const int np = c & 15, grp = c >> 4;
#pragma unroll
  for (int j = 0; j < 16; ++j) {
    const int c2 = grp * 16 + j;
    out[((size_t)(b * 256 + c2)) * N_ + n0 + np] = tile[c2 * 17 + np];
  }
}

// ---------------------------------------------------------------------------
extern "C" void kernel_launch(void* const* d_in, const int* in_sizes, int n_in,
                              void* d_out, int out_size, void* d_ws, size_t ws_size,
                              hipStream_t stream) {
  (void)in_sizes; (void)n_in; (void)out_size; (void)ws_size;
  const float* coords   = (const float*)d_in[0];
  const float* features = (const float*)d_in[1];
  const float* mlp1_w = (const float*)d_in[2];
  const float* mlp1_b = (const float*)d_in[3];
  const float* mlp1_g = (const float*)d_in[4];
  const float* mlp1_t = (const float*)d_in[5];
  const float* lse1_w = (const float*)d_in[6];
  const float* lse1_b = (const float*)d_in[7];
  const float* lse1_g = (const float*)d_in[8];
  const float* lse1_t = (const float*)d_in[9];
  const float* mlpp1_w = (const float*)d_in[10];
  const float* mlpp1_b = (const float*)d_in[11];
  const float* mlpp1_g = (const float*)d_in[12];
  const float* mlpp1_t = (const float*)d_in[13];
  const float* lse2_w = (const float*)d_in[14];
  const float* lse2_b = (const float*)d_in[15];
  const float* lse2_g = (const float*)d_in[16];
  const float* lse2_t = (const float*)d_in[17];
  const float* mlp2_w = (const float*)d_in[18];
  const float* mlp2_b = (const float*)d_in[19];
  const float* mlp2_g = (const float*)d_in[20];
  const float* mlp2_t = (const float*)d_in[21];
  const float* res_w = (const float*)d_in[22];
  const float* res_b = (const float*)d_in[23];
  const float* res_g = (const float*)d_in[24];
  const float* res_t = (const float*)d_in[25];
  const float* pool1_w = (const float*)d_in[26];
  const float* pool1_b = (const float*)d_in[27];
  const float* pool2_w = (const float*)d_in[28];
  const float* pool2_b = (const float*)d_in[29];

  float* wsf = (float*)d_ws;
  int* knn_i = (int*)d_ws;                 // 262144 ints
  float* knn_d = wsf + 262144;             // 262144
  float* y1 = wsf + 524288;                // (B,N,64)
  float* pooled1 = wsf + 1572864;          // (B,N,128)
  float* y2 = wsf + 3670016;               // (B,N,32)
  float* pooled2 = wsf + 4194304;          // (B,N,64)
  float* y3 = wsf + 5242880;               // (B,N,128)
  float* yr = wsf + 7340032;               // (B,N,128)
  double* dacc = (double*)(wsf + 9437184);
  double* mom = dacc;                      // 65
  double* sacc_mlp1 = dacc + 65;           // 128
  double* sacc_mlpp1 = dacc + 193;         // 64
  double* sacc_mlp2 = dacc + 257;          // 256
  double* sacc_res = dacc + 513;           // 256 -> ends 769
  float* fpar = wsf + 9437184 + 1600;
  float* w1f8 = fpar;                 // 512
  float* w2f8 = w1f8 + 512;           // 256
  short* wB1 = (short*)(w2f8 + 256);  // 16384 shorts
  short* wB2 = wB1 + 16384;           // 4096
  short* f1H = wB2 + 4096;            // 2048
  short* f1L = f1H + 2048;            // 2048
  short* f2H = f1L + 2048;            // 4096
  short* f2L = f2H + 4096;            // 4096
  short* f3H = f2L + 4096;            // 8192
  short* f3L = f3H + 8192;            // 8192
  short* fRH = f3L + 8192;            // 4096
  short* fRL = fRH + 4096;            // 4096

  hipMemsetAsync(dacc, 0, 769 * sizeof(double), stream);
  knn_kernel<<<dim3(N_ / 8, B_), 512, 0, stream>>>(coords, knn_i, knn_d);
  prep_kernel<<<11 + 256, 256, 0, stream>>>(pool1_w, pool2_w, wB1, wB2,
                                            mlp1_w, f1H, f1L, mlpp1_w, f2H, f2L,
                                            mlp2_w, f3H, f3L, res_w, fRH, fRL,
                                            coords, knn_i, knn_d, mom);
  gemmA_kernel<<<513, 256, 0, stream>>>(features, f1H, f1L, mlp1_b, y1, sacc_mlp1,
                                        fRH, fRL, res_b, yr, sacc_res, mom,
                                        lse1_w, lse1_b, lse1_g, lse1_t,
                                        lse2_w, lse2_b, lse2_g, lse2_t, w1f8, w2f8);
  pool_kernel<64, 64><<<B_ * N_ / 4, 256, 0, stream>>>(
      coords, knn_i, knn_d, w1f8, y1, sacc_mlp1, mlp1_g, mlp1_t, 0.2f, wB1, pool1_b, pooled1);
  gemm_mfma_kernel<128, 32, true><<<256, 256, 0, stream>>>(pooled1, f2H, f2L, mlpp1_b, y2, sacc_mlpp1);
  pool_kernel<32, 32><<<B_ * N_ / 4, 256, 0, stream>>>(
      coords, knn_i, knn_d, w2f8, y2, sacc_mlpp1, mlpp1_g, mlpp1_t, 0.0f, wB2, pool2_b, pooled2);
  gemm_mfma_kernel<64, 128, true><<<256, 256, 0, stream>>>(pooled2, f3H, f3L, mlp2_b, y3, sacc_mlp2);
  final_kernel<<<B_ * 512, 256, 0, stream>>>(y3, yr, sacc_mlp2, mlp2_g, mlp2_t,
                                             sacc_res, res_g, res_t, (float*)d_out);
}

// Round 17
// 390.939 us; speedup vs baseline: 2.5356x; 1.0022x over previous
//
#include <hip/hip_runtime.h>

static constexpr int N_ = 8192;
static constexpr int B_ = 2;
static constexpr int K_ = 16;

typedef __attribute__((ext_vector_type(8))) short bf16x8;
typedef __attribute__((ext_vector_type(4))) float f32x4;

__device__ __forceinline__ short f2bf(float f) {
  unsigned int u = __float_as_uint(f);
  unsigned int r = (u + 0x7FFFu + ((u >> 16) & 1u)) >> 16;
  return (short)r;
}
__device__ __forceinline__ float bf2f(short h) {
  return __uint_as_float(((unsigned int)(unsigned short)h) << 16);
}

// ---------------------------------------------------------------------------
// KNN: R3 body verbatim (best full-scan measurement: 127-128.5us). 1 query/
// wave, 512-thr block, 2048-pt tile, crossbar __shfl (insert chain on LDS
// pipe), refresh drain, _rn distances, in-lane self-exclusion.
// ---------------------------------------------------------------------------
__global__ __launch_bounds__(512) void knn_kernel(const float* __restrict__ coords,
                                                  int* __restrict__ oidx,
                                                  float* __restrict__ odist) {
  __shared__ float4 pts[2048];
  const int b = blockIdx.y;
  const int wv = threadIdx.x >> 6;
  const int lane = threadIdx.x & 63;
  const int q = blockIdx.x * 8 + wv;
  const float* cb = coords + (size_t)b * N_ * 3;
  const float qx = cb[q * 3 + 0], qy = cb[q * 3 + 1], qz = cb[q * 3 + 2];
  const float qsq = __fadd_rn(__fadd_rn(__fmul_rn(qx, qx), __fmul_rn(qy, qy)), __fmul_rn(qz, qz));
  float kd = INFINITY;  // sorted top-16 lives in lanes 0..15 (ascending)
  int ki = 0;
  float tau = INFINITY;
  for (int t0 = 0; t0 < N_; t0 += 2048) {
    __syncthreads();
    for (int i = threadIdx.x; i < 2048; i += 512) {
      const int p = t0 + i;
      const float x = cb[p * 3 + 0], y = cb[p * 3 + 1], z = cb[p * 3 + 2];
      const float sq = __fadd_rn(__fadd_rn(__fmul_rn(x, x), __fmul_rn(y, y)), __fmul_rn(z, z));
      pts[i] = make_float4(x, y, z, sq);
    }
    __syncthreads();
    for (int s = 0; s < 2048; s += 64) {
      const int j = t0 + s + lane;
      const float4 p = pts[s + lane];
      const float dot = __fadd_rn(__fadd_rn(__fmul_rn(qx, p.x), __fmul_rn(qy, p.y)), __fmul_rn(qz, p.z));
      float d2 = __fsub_rn(__fadd_rn(qsq, p.w), __fmul_rn(2.0f, dot));
      if (j == q) d2 = INFINITY;
      unsigned long long m = __ballot(d2 < tau);
      while (m) {
        const int src = __builtin_ctzll(m);  // ascending index -> tie stability
        const float dc = __shfl(d2, src);
        const int jc = t0 + s + src;
        const float sd = __shfl_up(kd, 1);
        const int si = __shfl_up(ki, 1);
        const bool c1 = kd > dc;             // strict: equals keep earlier entries
        const bool c2 = (lane > 0) && (sd > dc);
        kd = c1 ? (c2 ? sd : dc) : kd;
        ki = c1 ? (c2 ? si : jc) : ki;
        m &= (m - 1);
        tau = __shfl(kd, 15);
        m &= __ballot(d2 < tau);
      }
    }
  }
  if (lane < 16) {
    oidx[((size_t)b * N_ + q) * K_ + lane] = ki;
    odist[((size_t)b * N_ + q) * K_ + lane] = fmaxf(kd, 0.0f);
  }
}

// ---------------------------------------------------------------------------
// Moments helpers
// ---------------------------------------------------------------------------
__device__ __forceinline__ float snn_get(const float* SNN, int a, int b) {
  const int i = a < b ? a : b, j = a < b ? b : a;
  return SNN[i == 0 ? j : (i == 1 ? 2 + j : 3 + j)];
}
__device__ __forceinline__ float mom_mean(int i, const float* C, const float* SN, float Sd) {
  if (i < 3) return 16.0f * C[i];
  if (i < 6) return SN[i - 3];
  if (i < 9) return 16.0f * C[i - 6] - SN[i - 6];
  return Sd;
}
__device__ __forceinline__ float mom_prod(int i, int j, const float* C, const float* SN,
                                          const float* SNN, float Sd, float Sdd, const float* SND) {
  const int ti = i < 3 ? 0 : (i < 6 ? 1 : (i < 9 ? 2 : 3));
  const int tj = j < 3 ? 0 : (j < 6 ? 1 : (j < 9 ? 2 : 3));
  const int a = (ti == 3) ? 0 : (i - ti * 3);
  const int bb = (tj == 3) ? 0 : (j - tj * 3);
  if (ti == 0 && tj == 0) return 16.0f * C[a] * C[bb];
  if (ti == 0 && tj == 1) return C[a] * SN[bb];
  if (ti == 0 && tj == 2) return C[a] * (16.0f * C[bb] - SN[bb]);
  if (ti == 0 && tj == 3) return C[a] * Sd;
  if (ti == 1 && tj == 1) return snn_get(SNN, a, bb);
  if (ti == 1 && tj == 2) return C[bb] * SN[a] - snn_get(SNN, a, bb);
  if (ti == 1 && tj == 3) return SND[a];
  if (ti == 2 && tj == 2) return 16.0f * C[a] * C[bb] - C[a] * SN[bb] - C[bb] * SN[a] + snn_get(SNN, a, bb);
  if (ti == 2 && tj == 3) return C[a] * Sd - SND[a];
  return Sdd;
}

// ---------------------------------------------------------------------------
// PREP: blocks 0-10 weight conversion; blocks 11..266 k-parallel moments
// ---------------------------------------------------------------------------
template <int CI, int CO>
__device__ __forceinline__ void conv_frag_seg(const float* __restrict__ w, short* __restrict__ H,
                                              short* __restrict__ L, int tid, int nthr) {
  constexpr int NT = CO / 16;
  for (int i = tid; i < CI * CO; i += nthr) {
    const int j = i & 7, l = (i >> 3) & 63, tmp = i >> 9;
    const int tt = tmp % NT, cc = tmp / NT;
    const int c = cc * 32 + (l >> 4) * 8 + j;
    const int o = tt * 16 + (l & 15);
    const float v = w[o * CI + c];
    const short h = f2bf(v);
    H[i] = h;
    L[i] = f2bf(v - bf2f(h));
  }
}

__global__ __launch_bounds__(256) void prep_kernel(
    const float* __restrict__ pw1, const float* __restrict__ pw2,
    short* __restrict__ wB1, short* __restrict__ wB2,
    const float* __restrict__ wm1, short* __restrict__ f1H, short* __restrict__ f1L,
    const float* __restrict__ wmp, short* __restrict__ f2H, short* __restrict__ f2L,
    const float* __restrict__ wm2, short* __restrict__ f3H, short* __restrict__ f3L,
    const float* __restrict__ wrs, short* __restrict__ fRH, short* __restrict__ fRL,
    const float* __restrict__ coords, const int* __restrict__ knn_i,
    const float* __restrict__ knn_d, double* __restrict__ mom) {
  const int blk = blockIdx.x;
  if (blk < 11) {
    if (blk < 4) {
      for (int i = blk * 256 + threadIdx.x; i < 128 * 128; i += 1024) wB1[i] = f2bf(pw1[i]);
    } else if (blk == 4) {
      for (int i = threadIdx.x; i < 64 * 64; i += 256) wB2[i] = f2bf(pw2[i]);
    } else if (blk == 5) {
      conv_frag_seg<32, 64>(wm1, f1H, f1L, threadIdx.x, 256);
    } else if (blk == 6) {
      conv_frag_seg<128, 32>(wmp, f2H, f2L, threadIdx.x, 256);
    } else if (blk < 9) {
      conv_frag_seg<64, 128>(wm2, f3H, f3L, (blk - 7) * 256 + threadIdx.x, 512);
    } else {
      conv_frag_seg<32, 128>(wrs, fRH, fRL, (blk - 9) * 256 + threadIdx.x, 512);
    }
    return;
  }
  __shared__ float sh[16][65];
  const int mb = blk - 11;
  const int k = threadIdx.x & 15;
  const int pl = threadIdx.x >> 4;
  float accv = 0.0f;
  for (int batch = 0; batch < 4; ++batch) {
    const int pt = (mb * 4 + batch) * 16 + pl;
    const int b = pt >> 13, n = pt & (N_ - 1);
    const float* cb = coords + (size_t)b * N_ * 3;
    const float cx = cb[n * 3 + 0], cy = cb[n * 3 + 1], cz = cb[n * 3 + 2];
    const int id = knn_i[(size_t)pt * K_ + k];
    const float dd = knn_d[(size_t)pt * K_ + k];
    const float nx = cb[id * 3 + 0], ny = cb[id * 3 + 1], nz = cb[id * 3 + 2];
    float v[14] = {nx, ny, nz, nx * nx, nx * ny, nx * nz, ny * ny, ny * nz, nz * nz,
                   dd, dd * dd, nx * dd, ny * dd, nz * dd};
#pragma unroll
    for (int e = 0; e < 14; ++e) {
      v[e] += __shfl_xor(v[e], 1);
      v[e] += __shfl_xor(v[e], 2);
      v[e] += __shfl_xor(v[e], 4);
      v[e] += __shfl_xor(v[e], 8);
    }
    if (k == 0) {
      const float C[3] = {cx, cy, cz};
      const float SN[3] = {v[0], v[1], v[2]};
      const float SNN[6] = {v[3], v[4], v[5], v[6], v[7], v[8]};
      const float Sd = v[9], Sdd = v[10];
      const float SND[3] = {v[11], v[12], v[13]};
      float m65[65];
      int e = 0;
#pragma unroll
      for (int i = 0; i < 10; ++i) m65[e++] = mom_mean(i, C, SN, Sd);
#pragma unroll
      for (int i = 0; i < 10; ++i)
#pragma unroll
        for (int j = i; j < 10; ++j) m65[e++] = mom_prod(i, j, C, SN, SNN, Sd, Sdd, SND);
#pragma unroll
      for (int q2 = 0; q2 < 65; ++q2) sh[pl][q2] = m65[q2];
    }
    __syncthreads();
    if (threadIdx.x < 65) {
      float s = 0.0f;
#pragma unroll
      for (int r = 0; r < 16; ++r) s += sh[r][threadIdx.x];
      accv += s;
    }
    __syncthreads();
  }
  if (threadIdx.x < 65) atomicAdd(&mom[threadIdx.x], (double)accv);
}

// ---------------------------------------------------------------------------
// MFMA GEMM body + standalone kernel (hi/lo bf16 split => ~fp32 accuracy)
// ---------------------------------------------------------------------------
template <int CI, int CO, bool ROWMAJ>
__device__ __forceinline__ void gemm_body(const float* __restrict__ in,
                                          const short* __restrict__ fragH,
                                          const short* __restrict__ fragL,
                                          const float* __restrict__ bias,
                                          float* __restrict__ out,
                                          double* __restrict__ sacc,
                                          int blk, void* smem) {
  constexpr int NT = CO / 16;
  constexpr int NC = CI / 32;
  float (*part)[CO][2] = (float (*)[CO][2])smem;
  const int wv = threadIdx.x >> 6, l = threadIdx.x & 63;
  const int col = l & 15, quad = l >> 4;
  const int p0 = blk * 64 + wv * 16;
  const int pt = p0 + col;
  f32x4 d[NT];
#pragma unroll
  for (int t = 0; t < NT; ++t) {
    const float bv = bias[t * 16 + col];
    d[t][0] = bv; d[t][1] = bv; d[t][2] = bv; d[t][3] = bv;
  }
#pragma unroll
  for (int cc = 0; cc < NC; ++cc) {
    float xv[8];
    if (ROWMAJ) {
      const float* ip = in + (size_t)pt * CI + cc * 32 + quad * 8;
      *(float4*)&xv[0] = *(const float4*)ip;
      *(float4*)&xv[4] = *(const float4*)(ip + 4);
    } else {
      const int b = pt >> 13, n = pt & (N_ - 1);
      const float* ip = in + ((size_t)b * CI + cc * 32 + quad * 8) * N_ + n;
#pragma unroll
      for (int j = 0; j < 8; ++j) xv[j] = ip[(size_t)j * N_];
    }
    union { bf16x8 v; short u[8]; } AH, AL;
#pragma unroll
    for (int j = 0; j < 8; ++j) {
      const short h = f2bf(xv[j]);
      AH.u[j] = h;
      AL.u[j] = f2bf(xv[j] - bf2f(h));
    }
#pragma unroll
    for (int t = 0; t < NT; ++t) {
      const size_t fo = ((size_t)(cc * NT + t) * 64 + l) * 8;
      const bf16x8 BH = *(const bf16x8*)(fragH + fo);
      const bf16x8 BL = *(const bf16x8*)(fragL + fo);
      d[t] = __builtin_amdgcn_mfma_f32_16x16x32_bf16(AH.v, BH, d[t], 0, 0, 0);
      d[t] = __builtin_amdgcn_mfma_f32_16x16x32_bf16(AH.v, BL, d[t], 0, 0, 0);
      d[t] = __builtin_amdgcn_mfma_f32_16x16x32_bf16(AL.v, BH, d[t], 0, 0, 0);
    }
  }
#pragma unroll
  for (int t = 0; t < NT; ++t) {
#pragma unroll
    for (int r = 0; r < 4; ++r)
      out[(size_t)(p0 + quad * 4 + r) * CO + t * 16 + col] = d[t][r];
    float s1 = d[t][0] + d[t][1] + d[t][2] + d[t][3];
    float s2 = d[t][0] * d[t][0] + d[t][1] * d[t][1] + d[t][2] * d[t][2] + d[t][3] * d[t][3];
    s1 += __shfl_xor(s1, 16); s1 += __shfl_xor(s1, 32);
    s2 += __shfl_xor(s2, 16); s2 += __shfl_xor(s2, 32);
    if (quad == 0) { part[wv][t * 16 + col][0] = s1; part[wv][t * 16 + col][1] = s2; }
  }
  __syncthreads();
  if (threadIdx.x < CO) {
    const int o = threadIdx.x;
    atomicAdd(&sacc[o], (double)(part[0][o][0] + part[1][o][0] + part[2][o][0] + part[3][o][0]));
    atomicAdd(&sacc[CO + o], (double)(part[0][o][1] + part[1][o][1] + part[2][o][1] + part[3][o][1]));
  }
}

template <int CI, int CO, bool ROWMAJ>
__global__ __launch_bounds__(256) void gemm_mfma_kernel(const float* __restrict__ in,
                                                        const short* __restrict__ fragH,
                                                        const short* __restrict__ fragL,
                                                        const float* __restrict__ bias,
                                                        float* __restrict__ out,
                                                        double* __restrict__ sacc) {
  __shared__ float part[4][CO][2];
  gemm_body<CI, CO, ROWMAJ>(in, fragH, fragL, bias, out, sacc, blockIdx.x, (void*)part);
}

// ---------------------------------------------------------------------------
// GEMMA: blocks 0-255 mlp1, 256-511 res, block 512 lse setup (w8 fold)
// ---------------------------------------------------------------------------
__global__ __launch_bounds__(256) void gemmA_kernel(
    const float* __restrict__ features,
    const short* __restrict__ f1H, const short* __restrict__ f1L,
    const float* __restrict__ mlp1_b, float* __restrict__ y1, double* __restrict__ sacc1,
    const short* __restrict__ fRH, const short* __restrict__ fRL,
    const float* __restrict__ res_b, float* __restrict__ yr, double* __restrict__ saccR,
    const double* __restrict__ mom,
    const float* __restrict__ w1, const float* __restrict__ b1,
    const float* __restrict__ g1, const float* __restrict__ t1,
    const float* __restrict__ w2, const float* __restrict__ b2,
    const float* __restrict__ g2, const float* __restrict__ t2,
    float* __restrict__ w1f8, float* __restrict__ w2f8) {
  __shared__ float part[4][128][2];
  if (blockIdx.x < 256) {
    gemm_body<32, 64, false>(features, f1H, f1L, mlp1_b, y1, sacc1, blockIdx.x, (void*)part);
    return;
  }
  if (blockIdx.x < 512) {
    gemm_body<32, 128, false>(features, fRH, fRL, res_b, yr, saccR, blockIdx.x - 256, (void*)part);
    return;
  }
  const int t = threadIdx.x;
  double* mu = (double*)part;
  double* S = mu + 10;
  const double cnt = (double)B_ * N_ * K_;
  if (t < 10) mu[t] = mom[t] / cnt;
  if (t < 55) {
    int e = t, i = 0;
    while (e >= 10 - i) { e -= 10 - i; ++i; }
    const int j = i + e;
    const double v = mom[10 + t] / cnt;
    S[i * 10 + j] = v;
    S[j * 10 + i] = v;
  }
  __syncthreads();
  const float *w, *bias, *gg, *bt;
  float *wf;
  int c;
  if (t < 64) { w = w1; bias = b1; gg = g1; bt = t1; wf = w1f8; c = t; }
  else if (t < 96) { w = w2; bias = b2; gg = g2; bt = t2; wf = w2f8; c = t - 64; }
  else return;
  double wd[10];
#pragma unroll
  for (int d = 0; d < 10; ++d) wd[d] = (double)w[c * 10 + d];
  const double cbv = (double)bias[c];
  double mz = cbv;
  for (int d = 0; d < 10; ++d) mz += wd[d] * mu[d];
  double e2 = cbv * cbv;
  for (int d = 0; d < 10; ++d) e2 += 2.0 * cbv * wd[d] * mu[d];
  for (int d = 0; d < 10; ++d)
    for (int e = 0; e < 10; ++e) e2 += wd[d] * wd[e] * S[d * 10 + e];
  const double var = e2 - mz * mz;
  const double a = (double)gg[c] / sqrt(var + 1e-5);
  const double shift = (double)bt[c] - a * mz;
  wf[c * 8 + 0] = (float)(a * (wd[0] + wd[6]));
  wf[c * 8 + 1] = (float)(a * (wd[1] + wd[7]));
  wf[c * 8 + 2] = (float)(a * (wd[2] + wd[8]));
  wf[c * 8 + 3] = (float)(a * (wd[3] - wd[6]));
  wf[c * 8 + 4] = (float)(a * (wd[4] - wd[7]));
  wf[c * 8 + 5] = (float)(a * (wd[5] - wd[8]));
  wf[c * 8 + 6] = (float)(a * wd[9]);
  wf[c * 8 + 7] = (float)(a * cbv + shift);
}

// ---------------------------------------------------------------------------
// Fused LSE + attentive pool, MFMA scores (proven R10/R12/R15 version)
// ---------------------------------------------------------------------------
template <int CSF, int CF>
__global__ __launch_bounds__(256) void pool_kernel(
    const float* __restrict__ coords, const int* __restrict__ knn_i, const float* __restrict__ knn_d,
    const float* __restrict__ w8,
    const float* __restrict__ feat, const double* __restrict__ sfe,
    const float* __restrict__ gfe, const float* __restrict__ tfe,
    const float slope,
    const short* __restrict__ wB, const float* __restrict__ pb,
    float* __restrict__ out) {
  constexpr int C = CSF + CF;
  constexpr int CP = C + 4;
  constexpr int NT = C / 16;
  constexpr int NC = C / 32;
  __shared__ float xcat[4][16][CP];
  __shared__ float4 sp4[4][16];
  __shared__ float4 spc[4];
  const int g = threadIdx.x >> 6;
  const int l = threadIdx.x & 63;
  const int quad = l >> 4, col = l & 15;
  const int pid = blockIdx.x * 4 + g;
  const int b = pid >> 13, n = pid & (N_ - 1);
  const float* cb = coords + (size_t)b * N_ * 3;

  if (l < 16) {
    const int id = knn_i[(size_t)pid * K_ + l];
    const float dd = knn_d[(size_t)pid * K_ + l];
    sp4[g][l] = make_float4(cb[id * 3 + 0], cb[id * 3 + 1], cb[id * 3 + 2], dd);
    if (l == 0) spc[g] = make_float4(cb[n * 3 + 0], cb[n * 3 + 1], cb[n * 3 + 2], 0.0f);
  }
  if (l < CF) {
    const double cnt = (double)(B_ * N_);
    const double mean = sfe[l] / cnt;
    const double var = sfe[CF + l] / cnt - mean * mean;
    const double av = (double)gfe[l] / sqrt(var + 1e-5);
    const float af = (float)av;
    const float bfv = (float)((double)tfe[l] - av * mean);
    float v = feat[(size_t)pid * CF + l];
    v = af * v + bfv;
    v = (v >= 0.0f) ? v : slope * v;
#pragma unroll
    for (int j = 0; j < 16; ++j) xcat[g][j][CSF + l] = v;
  }
  __syncthreads();
  if (l < CSF) {
    const float4 wA = *(const float4*)(w8 + l * 8);      // P0,P1,P2,Q0
    const float4 wBv = *(const float4*)(w8 + l * 8 + 4); // Q1,Q2,wd,b'
    const float4 C4 = spc[g];
    const float tterm = wBv.w + wA.x * C4.x + wA.y * C4.y + wA.z * C4.z;
#pragma unroll
    for (int k = 0; k < 16; ++k) {
      const float4 nk = sp4[g][k];
      const float z = tterm + wA.w * nk.x + wBv.x * nk.y + wBv.y * nk.z + wBv.z * nk.w;
      xcat[g][k][l] = fmaxf(z, 0.0f);
    }
  }
  __syncthreads();
  f32x4 d[NT];
#pragma unroll
  for (int t = 0; t < NT; ++t) {
    const float pbv = pb[t * 16 + col];
    d[t][0] = pbv; d[t][1] = pbv; d[t][2] = pbv; d[t][3] = pbv;
  }
#pragma unroll
  for (int cc = 0; cc < NC; ++cc) {
    const float* xr = &xcat[g][col][cc * 32 + quad * 8];
    const float4 xa = *(const float4*)xr;
    const float4 xb = *(const float4*)(xr + 4);
    union { bf16x8 v; short u[8]; } A;
    A.u[0] = f2bf(xa.x); A.u[1] = f2bf(xa.y); A.u[2] = f2bf(xa.z); A.u[3] = f2bf(xa.w);
    A.u[4] = f2bf(xb.x); A.u[5] = f2bf(xb.y); A.u[6] = f2bf(xb.z); A.u[7] = f2bf(xb.w);
#pragma unroll
    for (int t = 0; t < NT; ++t) {
      const bf16x8 Bv = *(const bf16x8*)(wB + (size_t)(t * 16 + col) * C + cc * 32 + quad * 8);
      d[t] = __builtin_amdgcn_mfma_f32_16x16x32_bf16(A.v, Bv, d[t], 0, 0, 0);
    }
  }
#pragma unroll
  for (int t = 0; t < NT; ++t) {
    float mx = fmaxf(fmaxf(d[t][0], d[t][1]), fmaxf(d[t][2], d[t][3]));
    mx = fmaxf(mx, __shfl_xor(mx, 16));
    mx = fmaxf(mx, __shfl_xor(mx, 32));
    float e0 = __expf(d[t][0] - mx), e1 = __expf(d[t][1] - mx);
    float e2 = __expf(d[t][2] - mx), e3 = __expf(d[t][3] - mx);
    float s = e0 + e1 + e2 + e3;
    s += __shfl_xor(s, 16);
    s += __shfl_xor(s, 32);
    const int o = t * 16 + col;
    float part = e0 * xcat[g][quad * 4 + 0][o] + e1 * xcat[g][quad * 4 + 1][o] +
                 e2 * xcat[g][quad * 4 + 2][o] + e3 * xcat[g][quad * 4 + 3][o];
    part += __shfl_xor(part, 16);
    part += __shfl_xor(part, 32);
    if (quad == 0) out[(size_t)pid * C + o] = part / s;
  }
}

// ---------------------------------------------------------------------------
// Final: relu(affine(y3|yr)) with LDS transpose for coalesced writes
// ---------------------------------------------------------------------------
__global__ __launch_bounds__(256) void final_kernel(const float* __restrict__ y3,
                                                    const float* __restrict__ yr,
                                                    const double* __restrict__ s3,
                                                    const float* __restrict__ g3, const float* __restrict__ t3,
                                                    const double* __restrict__ sr,
                                                    const float* __restrict__ gr, const float* __restrict__ tr,
                                                    float* __restrict__ out) {
  __shared__ float tile[256 * 17];
  const int blk = blockIdx.x;
  const int b = blk >> 9;
  const int n0 = (blk & 511) << 4;
  const int c = threadIdx.x;
  const float* src;
  const double* sa;
  const float *gp, *tp;
  int cc;
  if (c < 128) { src = y3; sa = s3; gp = g3; tp = t3; cc = c; }
  else { src = yr; sa = sr; gp = gr; tp = tr; cc = c - 128; }
  const double cnt = (double)(B_ * N_);
  const double mean = sa[cc] / cnt;
  const double var = sa[128 + cc] / cnt - mean * mean;
  const double avd = (double)gp[cc] / sqrt(var + 1e-5);
  const float av = (float)avd;
  const float bv = (float)((double)tp[cc] - avd * mean);
#pragma unroll
  for (int nl = 0; nl < 16; ++nl) {
    const float x = av * src[((size_t)(b * N_ + n0 + nl)) * 128 + cc] + bv;
    tile[c * 17 + nl] = fmaxf(x, 0.0f);
  }
  __syncthreads();
  const int np = c & 15, grp = c >> 4;
#pragma unroll
  for (int j = 0; j < 16; ++j) {
    const int c2 = grp * 16 + j;
    out[((size_t)(b * 256 + c2)) * N_ + n0 + np] = tile[c2 * 17 + np];
  }
}

// ---------------------------------------------------------------------------
extern "C" void kernel_launch(void* const* d_in, const int* in_sizes, int n_in,
                              void* d_out, int out_size, void* d_ws, size_t ws_size,
                              hipStream_t stream) {
  (void)in_sizes; (void)n_in; (void)out_size; (void)ws_size;
  const float* coords   = (const float*)d_in[0];
  const float* features = (const float*)d_in[1];
  const float* mlp1_w = (const float*)d_in[2];
  const float* mlp1_b = (const float*)d_in[3];
  const float* mlp1_g = (const float*)d_in[4];
  const float* mlp1_t = (const float*)d_in[5];
  const float* lse1_w = (const float*)d_in[6];
  const float* lse1_b = (const float*)d_in[7];
  const float* lse1_g = (const float*)d_in[8];
  const float* lse1_t = (const float*)d_in[9];
  const float* mlpp1_w = (const float*)d_in[10];
  const float* mlpp1_b = (const float*)d_in[11];
  const float* mlpp1_g = (const float*)d_in[12];
  const float* mlpp1_t = (const float*)d_in[13];
  const float* lse2_w = (const float*)d_in[14];
  const float* lse2_b = (const float*)d_in[15];
  const float* lse2_g = (const float*)d_in[16];
  const float* lse2_t = (const float*)d_in[17];
  const float* mlp2_w = (const float*)d_in[18];
  const float* mlp2_b = (const float*)d_in[19];
  const float* mlp2_g = (const float*)d_in[20];
  const float* mlp2_t = (const float*)d_in[21];
  const float* res_w = (const float*)d_in[22];
  const float* res_b = (const float*)d_in[23];
  const float* res_g = (const float*)d_in[24];
  const float* res_t = (const float*)d_in[25];
  const float* pool1_w = (const float*)d_in[26];
  const float* pool1_b = (const float*)d_in[27];
  const float* pool2_w = (const float*)d_in[28];
  const float* pool2_b = (const float*)d_in[29];

  float* wsf = (float*)d_ws;
  int* knn_i = (int*)d_ws;                 // 262144 ints
  float* knn_d = wsf + 262144;             // 262144
  float* y1 = wsf + 524288;                // (B,N,64)
  float* pooled1 = wsf + 1572864;          // (B,N,128)
  float* y2 = wsf + 3670016;               // (B,N,32)
  float* pooled2 = wsf + 4194304;          // (B,N,64)
  float* y3 = wsf + 5242880;               // (B,N,128)
  float* yr = wsf + 7340032;               // (B,N,128)
  double* dacc = (double*)(wsf + 9437184);
  double* mom = dacc;                      // 65
  double* sacc_mlp1 = dacc + 65;           // 128
  double* sacc_mlpp1 = dacc + 193;         // 64
  double* sacc_mlp2 = dacc + 257;          // 256
  double* sacc_res = dacc + 513;           // 256 -> ends 769
  float* fpar = wsf + 9437184 + 1600;
  float* w1f8 = fpar;                 // 512
  float* w2f8 = w1f8 + 512;           // 256
  short* wB1 = (short*)(w2f8 + 256);  // 16384 shorts
  short* wB2 = wB1 + 16384;           // 4096
  short* f1H = wB2 + 4096;            // 2048
  short* f1L = f1H + 2048;            // 2048
  short* f2H = f1L + 2048;            // 4096
  short* f2L = f2H + 4096;            // 4096
  short* f3H = f2L + 4096;            // 8192
  short* f3L = f3H + 8192;            // 8192
  short* fRH = f3L + 8192;            // 4096
  short* fRL = fRH + 4096;            // 4096

  hipMemsetAsync(dacc, 0, 769 * sizeof(double), stream);
  knn_kernel<<<dim3(N_ / 8, B_), 512, 0, stream>>>(coords, knn_i, knn_d);
  prep_kernel<<<11 + 256, 256, 0, stream>>>(pool1_w, pool2_w, wB1, wB2,
                                            mlp1_w, f1H, f1L, mlpp1_w, f2H, f2L,
                                            mlp2_w, f3H, f3L, res_w, fRH, fRL,
                                            coords, knn_i, knn_d, mom);
  gemmA_kernel<<<513, 256, 0, stream>>>(features, f1H, f1L, mlp1_b, y1, sacc_mlp1,
                                        fRH, fRL, res_b, yr, sacc_res, mom,
                                        lse1_w, lse1_b, lse1_g, lse1_t,
                                        lse2_w, lse2_b, lse2_g, lse2_t, w1f8, w2f8);
  pool_kernel<64, 64><<<B_ * N_ / 4, 256, 0, stream>>>(
      coords, knn_i, knn_d, w1f8, y1, sacc_mlp1, mlp1_g, mlp1_t, 0.2f, wB1, pool1_b, pooled1);
  gemm_mfma_kernel<128, 32, true><<<256, 256, 0, stream>>>(pooled1, f2H, f2L, mlpp1_b, y2, sacc_mlpp1);
  pool_kernel<32, 32><<<B_ * N_ / 4, 256, 0, stream>>>(
      coords, knn_i, knn_d, w2f8, y2, sacc_mlpp1, mlpp1_g, mlpp1_t, 0.0f, wB2, pool2_b, pooled2);
  gemm_mfma_kernel<64, 128, true><<<256, 256, 0, stream>>>(pooled2, f3H, f3L, mlp2_b, y3, sacc_mlp2);
  final_kernel<<<B_ * 512, 256, 0, stream>>>(y3, yr, sacc_mlp2, mlp2_g, mlp2_t,
                                             sacc_res, res_g, res_t, (float*)d_out);
}